// Round 4
// baseline (700.777 us; speedup 1.0000x reference)
//
#include <hip/hip_runtime.h>
#include <hip/hip_bf16.h>

// ARMANet: 2x ARMAConv(K=1,T=1) + global mean pool + FC
// N=100000 nodes, E=1600000 edges, IN=HID=64, OUT=32, G=64 graphs.
// R23: pull gather restored (proven 52.7us) + atomic CSR build.
//  - R21/R22 push experiments: source-sweep cut FETCH 162->80MB but per-edge
//    shfl/DS cost made it 2x slower; Ts fits L3 so fetch reduction buys ~0.
//    Pull gather is final: 4 edges/wave, uint2 bf16 rows, shfl_xor reduce.
//  - CSR build replaced: bucket+sort (double-staged, barrier-heavy, ~2
//    passes over edge data) -> textbook atomic build:
//      K1: ndeg via global atomicAdd (wprep fused, blocks 0..127)
//      K2: single-block 1024-thr scan -> nstart, cur, dinv
//      K3: scatter es[atomicAdd(&cur[col])] = row  (order within dest
//          irrelevant for pull)
//  - MFMA dual GEMM (transposed C tile, uint2 epilogue), pool, fc unchanged.

#define NB 256

typedef unsigned int uint32;
typedef unsigned short ushort16;
typedef __attribute__((ext_vector_type(8))) short short8;   // 8 bf16 (4 VGPRs)
typedef __attribute__((ext_vector_type(4))) float f32x4;    // MFMA C/D

__device__ inline uint32 bf16rn(float f) {
    uint32 u = __float_as_uint(f);
    uint32 r = ((u >> 16) & 1u) + 0x7FFFu;
    return (u + r) >> 16;
}
__device__ inline uint32 pack_bf16(float a, float b) {
    return bf16rn(a) | (bf16rn(b) << 16);
}
__device__ inline float bflo(uint32 u) { return __uint_as_float(u << 16); }
__device__ inline float bfhi(uint32 u) { return __uint_as_float(u & 0xFFFF0000u); }

// ---------------- K1: degree count (+ fused weight prep) ----------------
// blocks [0,128): weights -> transposed split-bf16 table wt[m][d*64+k]
//   m: 0=init_hi 1=init_lo 2=root_hi 3=root_lo (x2 layers -> 8 mats).
// blocks [128,...): 2048 edges each, ndeg[col]++ via global atomics.
__global__ __launch_bounds__(256) void deg_kernel(
    const int* __restrict__ col, int* __restrict__ ndeg, int E,
    const float* __restrict__ W1i, const float* __restrict__ W1r,
    const float* __restrict__ W2i, const float* __restrict__ W2r,
    ushort16* __restrict__ wt) {
    int t = threadIdx.x;

    if (blockIdx.x < 128) {
        int idx = blockIdx.x * 256 + t;     // 8*4096 items over 128 blocks
        int m = idx >> 12;
        int r = idx & 4095;
        int d = r >> 6, k = r & 63;
        const float* W = (m < 2) ? W1i : (m < 4) ? W1r : (m < 6) ? W2i : W2r;
        float v = W[k * 64 + d];
        uint32 hi = bf16rn(v);
        uint32 outv;
        if (m & 1) {
            float hf = __uint_as_float(hi << 16);
            outv = bf16rn(v - hf);
        } else {
            outv = hi;
        }
        wt[(size_t)m * 4096 + d * 64 + k] = (unsigned short)outv;
        return;
    }

    int e0 = (blockIdx.x - 128) * 2048 + t * 8;
    if (e0 + 8 <= E) {
        int4 a = *(const int4*)&col[e0];
        int4 b = *(const int4*)&col[e0 + 4];
        atomicAdd(&ndeg[a.x], 1); atomicAdd(&ndeg[a.y], 1);
        atomicAdd(&ndeg[a.z], 1); atomicAdd(&ndeg[a.w], 1);
        atomicAdd(&ndeg[b.x], 1); atomicAdd(&ndeg[b.y], 1);
        atomicAdd(&ndeg[b.z], 1); atomicAdd(&ndeg[b.w], 1);
    } else {
        for (int k = 0; k < 8; ++k)
            if (e0 + k < E) atomicAdd(&ndeg[col[e0 + k]], 1);
    }
}

// ---------------- K2: single-block exclusive scan -> nstart, cur, dinv ----------------
__global__ __launch_bounds__(1024) void scan_kernel(
    const int* __restrict__ ndeg, int* __restrict__ nstart,
    int* __restrict__ cur, float* __restrict__ dinv, int n) {
    __shared__ int wtot[16];
    __shared__ int wexc[16];
    int t = threadIdx.x;
    int per = (n + 1023) / 1024;          // 98
    int s0 = min(t * per, n);
    int s1 = min(s0 + per, n);
    int sum = 0;
    for (int i = s0; i < s1; ++i) sum += ndeg[i];

    // wave-level inclusive scan of per-thread sums
    int lane = t & 63, w = t >> 6;
    int inc = sum;
    for (int off = 1; off < 64; off <<= 1) {
        int v = __shfl_up(inc, off);
        if (lane >= off) inc += v;
    }
    if (lane == 63) wtot[w] = inc;
    __syncthreads();
    if (t == 0) {
        int acc = 0;
        for (int i = 0; i < 16; ++i) { wexc[i] = acc; acc += wtot[i]; }
    }
    __syncthreads();
    int base = wexc[w] + (inc - sum);     // exclusive prefix for this thread
    for (int i = s0; i < s1; ++i) {
        int d = ndeg[i];
        nstart[i] = base;
        cur[i] = base;
        dinv[i] = d ? rsqrtf((float)d) : 0.0f;
        base += d;
    }
}

// ---------------- K3: scatter edges into CSR ----------------
__global__ __launch_bounds__(256) void scatter_kernel(
    const int* __restrict__ row, const int* __restrict__ col,
    int* __restrict__ cur, int* __restrict__ es, int E) {
    int t = threadIdx.x;
    int e0 = blockIdx.x * 2048 + t * 8;
    if (e0 + 8 <= E) {
        int4 ca = *(const int4*)&col[e0];
        int4 cb = *(const int4*)&col[e0 + 4];
        int4 ra = *(const int4*)&row[e0];
        int4 rb = *(const int4*)&row[e0 + 4];
        es[atomicAdd(&cur[ca.x], 1)] = ra.x;
        es[atomicAdd(&cur[ca.y], 1)] = ra.y;
        es[atomicAdd(&cur[ca.z], 1)] = ra.z;
        es[atomicAdd(&cur[ca.w], 1)] = ra.w;
        es[atomicAdd(&cur[cb.x], 1)] = rb.x;
        es[atomicAdd(&cur[cb.y], 1)] = rb.y;
        es[atomicAdd(&cur[cb.z], 1)] = rb.z;
        es[atomicAdd(&cur[cb.w], 1)] = rb.w;
    } else {
        for (int k = 0; k < 8; ++k)
            if (e0 + k < E) es[atomicAdd(&cur[col[e0 + k]], 1)] = row[e0 + k];
    }
}

// ---------------- MFMA dual GEMM (fused f32->bf16 X staging) ----------------
// Ts = bf16(dinv .* (X@Winit)), Rs = bf16(X@Wroot + bias).
// X: f32 (xf32=1, layer 1) or packed bf16 uint rows (xf32=0, layer 2).
// Swapped MFMA operands -> transposed C tile: each thread holds 4 consecutive
// dims of ONE node -> packed uint2 stores, coalesced per-node dinv loads.
__global__ __launch_bounds__(256) void gemm_mfma(
    const void* __restrict__ Xin,
    const ushort16* __restrict__ wt4,
    const float* __restrict__ bias, const float* __restrict__ dinv,
    ushort16* __restrict__ Ts, ushort16* __restrict__ Rs, int n, int xf32) {
    __shared__ unsigned short sXs[64 * 72];   // 9216 B, row stride 72 bf16
    int t = threadIdx.x;
    int node0 = blockIdx.x * 64;

    if (xf32) {
        const float* X = (const float*)Xin;
        for (int i = t; i < 1024; i += 256) {
            int r = i >> 4, c4 = (i & 15) * 4;
            int node = node0 + r;
            float4 v = make_float4(0.f, 0.f, 0.f, 0.f);
            if (node < n) v = *(const float4*)&X[(size_t)node * 64 + c4];
            *(uint32*)&sXs[r * 72 + c4] = pack_bf16(v.x, v.y);
            *(uint32*)&sXs[r * 72 + c4 + 2] = pack_bf16(v.z, v.w);
        }
    } else {
        const uint32* Xb2 = (const uint32*)Xin;
        for (int i = t; i < 512; i += 256) {
            int r = i >> 3, kg = i & 7;
            int node = node0 + r;
            uint4 v = make_uint4(0u, 0u, 0u, 0u);
            if (node < n) v = *(const uint4*)&Xb2[(size_t)node * 32 + kg * 4];
            *(uint4*)&sXs[r * 72 + kg * 8] = v;
        }
    }

    int w = t >> 6;
    int lane = t & 63;
    int q = lane >> 4;
    int col = lane & 15;
    int dim = w * 16 + col;

    short8 bih[2], bil[2], brh[2], brl[2];
#pragma unroll
    for (int kh = 0; kh < 2; ++kh) {
        size_t o = (size_t)dim * 64 + kh * 32 + q * 8;
        bih[kh] = *(const short8*)&wt4[0 * 4096 + o];
        bil[kh] = *(const short8*)&wt4[1 * 4096 + o];
        brh[kh] = *(const short8*)&wt4[2 * 4096 + o];
        brl[kh] = *(const short8*)&wt4[3 * 4096 + o];
    }
    float4 bias4 = *(const float4*)&bias[w * 16 + q * 4];
    __syncthreads();

    unsigned short* TsU = (unsigned short*)Ts;
    unsigned short* RsU = (unsigned short*)Rs;

#pragma unroll
    for (int mt = 0; mt < 4; ++mt) {
        int rbase = mt * 16 + col;
        short8 a0 = *(const short8*)&sXs[rbase * 72 + q * 8];
        short8 a1 = *(const short8*)&sXs[rbase * 72 + 32 + q * 8];
        f32x4 accT = {0.f, 0.f, 0.f, 0.f};
        f32x4 accR = {0.f, 0.f, 0.f, 0.f};
        accT = __builtin_amdgcn_mfma_f32_16x16x32_bf16(bih[0], a0, accT, 0, 0, 0);
        accT = __builtin_amdgcn_mfma_f32_16x16x32_bf16(bih[1], a1, accT, 0, 0, 0);
        accT = __builtin_amdgcn_mfma_f32_16x16x32_bf16(bil[0], a0, accT, 0, 0, 0);
        accT = __builtin_amdgcn_mfma_f32_16x16x32_bf16(bil[1], a1, accT, 0, 0, 0);
        accR = __builtin_amdgcn_mfma_f32_16x16x32_bf16(brh[0], a0, accR, 0, 0, 0);
        accR = __builtin_amdgcn_mfma_f32_16x16x32_bf16(brh[1], a1, accR, 0, 0, 0);
        accR = __builtin_amdgcn_mfma_f32_16x16x32_bf16(brl[0], a0, accR, 0, 0, 0);
        accR = __builtin_amdgcn_mfma_f32_16x16x32_bf16(brl[1], a1, accR, 0, 0, 0);

        int node = node0 + mt * 16 + col;
        if (node < n) {
            float dv = dinv[node];
            uint2 pT, pR;
            pT.x = pack_bf16(accT[0] * dv, accT[1] * dv);
            pT.y = pack_bf16(accT[2] * dv, accT[3] * dv);
            pR.x = pack_bf16(accR[0] + bias4.x, accR[1] + bias4.y);
            pR.y = pack_bf16(accR[2] + bias4.z, accR[3] + bias4.w);
            size_t o = (size_t)node * 64 + w * 16 + q * 4;
            *(uint2*)&TsU[o] = pT;
            *(uint2*)&RsU[o] = pR;
        }
    }
}

// ---------------- fused gather-propagate + relu: 4 edges per wave, uint2 loads ----------------
// Quarter q = lane>>4 handles edges {j+q, j+4+q, j+8+q, j+12+q}; lane covers
// dims [4*d4, 4*d4+4) via 8B load. Cross-quarter shfl_xor(16/32) reduction.
__global__ __launch_bounds__(256) void gather_fused(
    const uint2* __restrict__ Ts2, const uint2* __restrict__ Rs2,
    const int* __restrict__ es, const int* __restrict__ nstart,
    const int* __restrict__ ndeg, const float* __restrict__ dinv,
    uint2* __restrict__ Hb2, int n) {
    int c = blockIdx.x * 4 + (threadIdx.x >> 6);
    if (c >= n) return;
    int lane = threadIdx.x & 63;
    int q = lane >> 4;    // edge slot 0..3
    int d4 = lane & 15;   // dim quad
    int deg = ndeg[c];
    int s0 = nstart[c];
    float a0 = 0.f, a1 = 0.f, a2 = 0.f, a3 = 0.f;
    for (int base = 0; base < deg; base += 64) {
        int m = min(deg - base, 64);
        int sid = (lane < m) ? es[s0 + base + lane] : 0;
        for (int j = 0; j < m; j += 16) {
            int e0 = j + q, e1 = j + 4 + q, e2 = j + 8 + q, e3 = j + 12 + q;
            int r0 = __shfl(sid, e0);
            int r1 = __shfl(sid, e1);
            int r2 = __shfl(sid, e2);
            int r3 = __shfl(sid, e3);
            uint2 z = make_uint2(0u, 0u);
            uint2 v0 = (e0 < m) ? Ts2[(size_t)r0 * 16 + d4] : z;
            uint2 v1 = (e1 < m) ? Ts2[(size_t)r1 * 16 + d4] : z;
            uint2 v2 = (e2 < m) ? Ts2[(size_t)r2 * 16 + d4] : z;
            uint2 v3 = (e3 < m) ? Ts2[(size_t)r3 * 16 + d4] : z;
            a0 += bflo(v0.x) + bflo(v1.x) + bflo(v2.x) + bflo(v3.x);
            a1 += bfhi(v0.x) + bfhi(v1.x) + bfhi(v2.x) + bfhi(v3.x);
            a2 += bflo(v0.y) + bflo(v1.y) + bflo(v2.y) + bflo(v3.y);
            a3 += bfhi(v0.y) + bfhi(v1.y) + bfhi(v2.y) + bfhi(v3.y);
        }
    }
    a0 += __shfl_xor(a0, 16); a0 += __shfl_xor(a0, 32);
    a1 += __shfl_xor(a1, 16); a1 += __shfl_xor(a1, 32);
    a2 += __shfl_xor(a2, 16); a2 += __shfl_xor(a2, 32);
    a3 += __shfl_xor(a3, 16); a3 += __shfl_xor(a3, 32);
    if (lane < 16) {
        float dc = dinv[c];
        uint2 ur = Rs2[(size_t)c * 16 + d4];
        float h0 = fmaxf(fmaf(dc, a0, bflo(ur.x)), 0.0f);
        float h1 = fmaxf(fmaf(dc, a1, bfhi(ur.x)), 0.0f);
        float h2 = fmaxf(fmaf(dc, a2, bflo(ur.y)), 0.0f);
        float h3 = fmaxf(fmaf(dc, a3, bfhi(ur.y)), 0.0f);
        Hb2[(size_t)c * 16 + d4] = make_uint2(pack_bf16(h0, h1), pack_bf16(h2, h3));
    }
}

// ---------------- mean-pool over sorted batch (bf16x2 loads, half-wave/node) ----------------
__global__ __launch_bounds__(256) void pool_kernel(
    const uint32* __restrict__ Hb, const int* __restrict__ batch,
    float* __restrict__ pooled, float* __restrict__ cnt, int n) {
    __shared__ float sAcc[64 * 64];
    __shared__ float sCnt[64];
    int tid = threadIdx.x;
    for (int i = tid; i < 4096; i += 256) sAcc[i] = 0.0f;
    if (tid < 64) sCnt[tid] = 0.0f;
    __syncthreads();

    int w = tid >> 6, lane = tid & 63;
    int half = lane >> 5, d2 = lane & 31;
    int s = blockIdx.x * 256 + w * 64;
    int e = min(s + 64, n);
    float a0 = 0.0f, a1 = 0.0f, c = 0.0f;
    int gcur = -1;
    for (int i = s + half; i < e; i += 2) {
        int g = batch[i];
        if (g != gcur) {
            if (gcur >= 0) {
                atomicAdd(&sAcc[gcur * 64 + 2 * d2], a0);
                atomicAdd(&sAcc[gcur * 64 + 2 * d2 + 1], a1);
                if (d2 == 0) atomicAdd(&sCnt[gcur], c);
            }
            gcur = g; a0 = 0.0f; a1 = 0.0f; c = 0.0f;
        }
        uint32 u = Hb[(size_t)i * 32 + d2];
        a0 += bflo(u);
        a1 += bfhi(u);
        c += 1.0f;
    }
    if (gcur >= 0) {
        atomicAdd(&sAcc[gcur * 64 + 2 * d2], a0);
        atomicAdd(&sAcc[gcur * 64 + 2 * d2 + 1], a1);
        if (d2 == 0) atomicAdd(&sCnt[gcur], c);
    }
    __syncthreads();
    for (int i = tid; i < 4096; i += 256) {
        float v = sAcc[i];
        if (v != 0.0f) atomicAdd(&pooled[i], v);
    }
    if (tid < 64) {
        float v = sCnt[tid];
        if (v != 0.0f) atomicAdd(&cnt[tid], v);
    }
}

// ---------------- out[g,o] = (pooled[g,:]/max(cnt,1)) @ fcw + fcb ----------------
__global__ void final_fc(const float* __restrict__ pooled, const float* __restrict__ cnt,
                         const float* __restrict__ fcw, const float* __restrict__ fcb,
                         float* __restrict__ out) {
    int idx = blockIdx.x * 256 + threadIdx.x;
    if (idx >= 64 * 32) return;
    int g = idx >> 5, o = idx & 31;
    float c = fmaxf(cnt[g], 1.0f);
    float acc = 0.0f;
#pragma unroll
    for (int k = 0; k < 64; ++k) acc = fmaf(pooled[g * 64 + k], fcw[k * 32 + o], acc);
    out[idx] = acc / c + fcb[o];
}

extern "C" void kernel_launch(void* const* d_in, const int* in_sizes, int n_in,
                              void* d_out, int out_size, void* d_ws, size_t ws_size,
                              hipStream_t stream) {
    const float* x       = (const float*)d_in[0];
    const int*   eidx    = (const int*)d_in[1];
    const int*   batch   = (const int*)d_in[2];
    const float* w1_init = (const float*)d_in[3];
    const float* w1_root = (const float*)d_in[4];
    const float* b1      = (const float*)d_in[5];
    const float* w2_init = (const float*)d_in[6];
    const float* w2_root = (const float*)d_in[7];
    const float* b2      = (const float*)d_in[8];
    const float* fc_w    = (const float*)d_in[9];
    const float* fc_b    = (const float*)d_in[10];
    float* out = (float*)d_out;

    const int N = in_sizes[0] / 64;
    const int E = in_sizes[1] / 2;
    const int* row = eidx;
    const int* col = eidx + E;

    // workspace (4-byte units):
    // [zeroed] ndeg(N) | pooled(4096) | cnt(64)
    // nstart(N) | cur(N) | dinv(N) | wt(16384) | es(E) | Ts(N*32) | Rs(N*32) | Hb(N*32)
    int*   ndeg   = (int*)d_ws;
    float* pooled = (float*)(ndeg + N);
    float* cnt    = pooled + 64 * 64;
    int*   nstart = (int*)(cnt + 64);
    int*   cur    = nstart + N;
    float* dinv   = (float*)(cur + N);
    uint32* wtU   = (uint32*)(dinv + N);            // 16384 uints (64 KB)
    int*   es     = (int*)(wtU + 16384);            // E ints
    uint32* Ts    = (uint32*)(es + E);              // N*32
    uint32* Rs    = Ts + (size_t)N * 32;            // N*32
    uint32* Hb    = Rs + (size_t)N * 32;            // N*32
    ushort16* wt  = (ushort16*)wtU;

    hipMemsetAsync(ndeg, 0, (size_t)(N + 64 * 64 + 64) * sizeof(int), stream);

    const int EB = (E + 2047) / 2048;   // 782 edge blocks
    deg_kernel<<<128 + EB, 256, 0, stream>>>(col, ndeg, E,
                                             w1_init, w1_root, w2_init, w2_root, wt);
    scan_kernel<<<1, 1024, 0, stream>>>(ndeg, nstart, cur, dinv, N);
    scatter_kernel<<<EB, 256, 0, stream>>>(row, col, cur, es, E);

    // layer 1 (f32 input); wt = mats 0..3 (layer-1 init_hi/init_lo/root_hi/root_lo)
    gemm_mfma<<<(N + 63) / 64, 256, 0, stream>>>(x, wt, b1, dinv,
                                                 (ushort16*)Ts, (ushort16*)Rs, N, 1);
    gather_fused<<<(N + 3) / 4, 256, 0, stream>>>((const uint2*)Ts, (const uint2*)Rs,
                                                  es, nstart, ndeg, dinv, (uint2*)Hb, N);

    // layer 2 (bf16 input); wt + 4*4096 ushorts = mats 4..7 (layer-2 weights)
    gemm_mfma<<<(N + 63) / 64, 256, 0, stream>>>(Hb, wt + (size_t)4 * 4096, b2, dinv,
                                                 (ushort16*)Ts, (ushort16*)Rs, N, 0);
    gather_fused<<<(N + 3) / 4, 256, 0, stream>>>((const uint2*)Ts, (const uint2*)Rs,
                                                  es, nstart, ndeg, dinv, (uint2*)Hb, N);

    // pool + FC
    pool_kernel<<<(N + 255) / 256, 256, 0, stream>>>(Hb, batch, pooled, cnt, N);
    final_fc<<<(64 * 32 + 255) / 256, 256, 0, stream>>>(pooled, cnt, fc_w, fc_b, out);
}

// Round 5
// 330.433 us; speedup vs baseline: 2.1208x; 2.1208x over previous
//
#include <hip/hip_runtime.h>
#include <hip/hip_bf16.h>

// ARMANet: 2x ARMAConv(K=1,T=1) + global mean pool + FC
// N=100000 nodes, E=1600000 edges, IN=HID=64, OUT=32, G=64 graphs.
// R24: restoration + gemm experiment.
//  - R23 verdict: global-atomic CSR build is 50-100x worse per-op (scan 280us
//    single-block, deg+scatter ~160us of device-scope atomics). Bucket+csr
//    build (LDS-atomic, proven ~35-40us) restored exactly (R20 form).
//  - Pull gather restored exactly (proven 52.7us; R21/R22 push was 2x worse).
//  - gemm_mfma rewritten LDS-FREE: swapped-operand tile lets each lane load
//    its X fragment straight from global (16B at X[node0+mt*16+col][q*8],
//    coalesced 2KB/wave, 4-wave redundancy L1-absorbed). No barriers, no
//    staging VALU. Bit-identical numerics (same MFMA order + rounding).
//  - final_fc fused into pool_kernel tail via last-block-done counter
//    (device-scope atomics + threadfence + agent-scope loads): -1 dispatch.

#define NB 256
#define CAP 5120
#define MAXB 400
#define P1_CHUNK 2048

typedef unsigned int uint32;
typedef unsigned short ushort16;
typedef __attribute__((ext_vector_type(8))) short short8;   // 8 bf16 (4 VGPRs)
typedef __attribute__((ext_vector_type(4))) float f32x4;    // MFMA C/D

__device__ inline uint32 bf16rn(float f) {
    uint32 u = __float_as_uint(f);
    uint32 r = ((u >> 16) & 1u) + 0x7FFFu;
    return (u + r) >> 16;
}
__device__ inline uint32 pack_bf16(float a, float b) {
    return bf16rn(a) | (bf16rn(b) << 16);
}
__device__ inline float bflo(uint32 u) { return __uint_as_float(u << 16); }
__device__ inline float bfhi(uint32 u) { return __uint_as_float(u & 0xFFFF0000u); }

union frag_u {
    uint4 u4;
    short8 s8;
    uint32 u[4];
};

// ---------------- stage 1: bucket edges by destination (+ fused weight prep) ----------------
// blocks [0,128): weights -> transposed split-bf16 table wt[m][d*64+k]
//   m: 0=init_hi 1=init_lo 2=root_hi 3=root_lo (x2 layers -> 8 mats).
// blocks [128,...): 2048-edge chunk bucketing by col>>8.
__global__ __launch_bounds__(256) void bucket_kernel(
    const int* __restrict__ row, const int* __restrict__ col,
    uint32* __restrict__ bpack, int* __restrict__ bcnt, int E,
    const float* __restrict__ W1i, const float* __restrict__ W1r,
    const float* __restrict__ W2i, const float* __restrict__ W2r,
    ushort16* __restrict__ wt) {
    __shared__ int hist[MAXB];
    __shared__ int ofs[MAXB];
    __shared__ int cur[MAXB];
    __shared__ int gbase[MAXB];
    __shared__ int s[256];
    __shared__ uint32 stage[P1_CHUNK];
    __shared__ unsigned short stage_bk[P1_CHUNK];

    int t = threadIdx.x;

    if (blockIdx.x < 128) {
        // ---- wprep role ----
        int idx = blockIdx.x * 256 + t;     // 8*4096 items over 128 blocks
        int m = idx >> 12;
        int r = idx & 4095;
        int d = r >> 6, k = r & 63;
        const float* W = (m < 2) ? W1i : (m < 4) ? W1r : (m < 6) ? W2i : W2r;
        float v = W[k * 64 + d];
        uint32 hi = bf16rn(v);
        uint32 outv;
        if (m & 1) {
            float hf = __uint_as_float(hi << 16);
            outv = bf16rn(v - hf);
        } else {
            outv = hi;
        }
        wt[(size_t)m * 4096 + d * 64 + k] = (unsigned short)outv;
        return;
    }

    for (int i = t; i < MAXB; i += 256) hist[i] = 0;
    __syncthreads();

    int e0 = (blockIdx.x - 128) * P1_CHUNK;
    int cntE = min(E - e0, P1_CHUNK);

    for (int i = t; i < cntE; i += 256) {
        int c = col[e0 + i];
        atomicAdd(&hist[c >> 8], 1);
    }
    __syncthreads();

    int i2 = 2 * t;
    int a = (i2 < MAXB) ? hist[i2] : 0;
    int b = (i2 + 1 < MAXB) ? hist[i2 + 1] : 0;
    s[t] = a + b;
    __syncthreads();
    for (int off = 1; off < 256; off <<= 1) {
        int x = (t >= off) ? s[t - off] : 0;
        __syncthreads();
        s[t] += x;
        __syncthreads();
    }
    int excl = (t > 0) ? s[t - 1] : 0;
    if (i2 < MAXB) ofs[i2] = excl;
    if (i2 + 1 < MAXB) ofs[i2 + 1] = excl + a;
    __syncthreads();

    for (int i = t; i < MAXB; i += 256) {
        cur[i] = ofs[i];
        gbase[i] = hist[i] ? atomicAdd(&bcnt[i], hist[i]) : 0;
    }
    __syncthreads();

    for (int i = t; i < cntE; i += 256) {
        int c = col[e0 + i];
        int r = row[e0 + i];
        int bk = c >> 8;
        int k = atomicAdd(&cur[bk], 1);
        stage[k] = ((uint32)(c & 255) << 24) | (uint32)r;
        stage_bk[k] = (unsigned short)bk;
    }
    __syncthreads();

    for (int i = t; i < cntE; i += 256) {
        uint32 pk = stage[i];
        int bk = stage_bk[i];
        int gd = gbase[bk] + (i - ofs[bk]);
        if (gd < CAP) bpack[(size_t)bk * CAP + gd] = pk;
    }
}

// ---------------- stage 2: per-bucket counting sort -> CSR + dinv ----------------
__global__ __launch_bounds__(1024) void csr_kernel(
    const uint32* __restrict__ bpack, const int* __restrict__ bcnt,
    int* __restrict__ es, int* __restrict__ nstart, int* __restrict__ ndeg,
    float* __restrict__ dinv, int n) {
    __shared__ uint32 sbp[CAP];   // 20 KB
    __shared__ int h[NB];
    __shared__ int s[NB];
    __shared__ int cur[NB];
    int b = blockIdx.x, t = threadIdx.x;
    if (t < NB) h[t] = 0;
    __syncthreads();
    int cnt = min(bcnt[b], CAP);
    size_t base = (size_t)b * CAP;
    for (int i = t; i < cnt; i += 1024) {
        uint32 pk = bpack[base + i];
        sbp[i] = pk;
        atomicAdd(&h[pk >> 24], 1);
    }
    __syncthreads();
    if (t < NB) s[t] = h[t];
    __syncthreads();
    for (int off = 1; off < NB; off <<= 1) {
        int x = 0;
        if (t < NB && t >= off) x = s[t - off];
        __syncthreads();
        if (t < NB) s[t] += x;
        __syncthreads();
    }
    if (t < NB) {
        int myofs = s[t] - h[t];
        cur[t] = myofs;
        int node = b * NB + t;
        if (node < n) {
            nstart[node] = (int)base + myofs;
            ndeg[node] = h[t];
            dinv[node] = h[t] ? rsqrtf((float)h[t]) : 0.0f;
        }
    }
    __syncthreads();
    for (int i = t; i < cnt; i += 1024) {
        uint32 pk = sbp[i];
        int cl = (int)(pk >> 24);
        int p = atomicAdd(&cur[cl], 1);
        es[base + p] = (int)(pk & 0xFFFFFFu);
    }
}

// ---------------- MFMA dual GEMM, LDS-free ----------------
// Ts = bf16(dinv .* (X@Winit)), Rs = bf16(X@Wroot + bias).
// X: f32 (xf32=1, layer 1) or packed bf16 uint rows (xf32=0, layer 2).
// Swapped MFMA operands -> transposed C tile. X fragments loaded DIRECTLY
// from global: lane (q,col) reads 16B at row node0+mt*16+col, byte offset
// q*16 (a0) / 64+q*16 (a1). Wave = 16 rows x 64B, fully coalesced; 4-wave
// redundancy absorbed by L1. No LDS, no barriers. Numerics identical to the
// staged version (same rounding, same MFMA order).
__global__ __launch_bounds__(256) void gemm_mfma(
    const void* __restrict__ Xin,
    const ushort16* __restrict__ wt4,
    const float* __restrict__ bias, const float* __restrict__ dinv,
    ushort16* __restrict__ Ts, ushort16* __restrict__ Rs, int n, int xf32) {
    int t = threadIdx.x;
    int node0 = blockIdx.x * 64;

    int w = t >> 6;
    int lane = t & 63;
    int q = lane >> 4;
    int col = lane & 15;
    int dim = w * 16 + col;

    short8 bih[2], bil[2], brh[2], brl[2];
#pragma unroll
    for (int kh = 0; kh < 2; ++kh) {
        size_t o = (size_t)dim * 64 + kh * 32 + q * 8;
        bih[kh] = *(const short8*)&wt4[0 * 4096 + o];
        bil[kh] = *(const short8*)&wt4[1 * 4096 + o];
        brh[kh] = *(const short8*)&wt4[2 * 4096 + o];
        brl[kh] = *(const short8*)&wt4[3 * 4096 + o];
    }
    float4 bias4 = *(const float4*)&bias[w * 16 + q * 4];

    unsigned short* TsU = (unsigned short*)Ts;
    unsigned short* RsU = (unsigned short*)Rs;

#pragma unroll
    for (int mt = 0; mt < 4; ++mt) {
        int node = node0 + mt * 16 + col;
        frag_u a0, a1;
        if (xf32) {
            float4 f0 = make_float4(0.f, 0.f, 0.f, 0.f), f1 = f0, f2 = f0, f3 = f0;
            if (node < n) {
                const float* Xr = (const float*)Xin + (size_t)node * 64 + q * 8;
                f0 = *(const float4*)(Xr);
                f1 = *(const float4*)(Xr + 4);
                f2 = *(const float4*)(Xr + 32);
                f3 = *(const float4*)(Xr + 36);
            }
            a0.u[0] = pack_bf16(f0.x, f0.y);
            a0.u[1] = pack_bf16(f0.z, f0.w);
            a0.u[2] = pack_bf16(f1.x, f1.y);
            a0.u[3] = pack_bf16(f1.z, f1.w);
            a1.u[0] = pack_bf16(f2.x, f2.y);
            a1.u[1] = pack_bf16(f2.z, f2.w);
            a1.u[2] = pack_bf16(f3.x, f3.y);
            a1.u[3] = pack_bf16(f3.z, f3.w);
        } else {
            a0.u4 = make_uint4(0u, 0u, 0u, 0u);
            a1.u4 = make_uint4(0u, 0u, 0u, 0u);
            if (node < n) {
                const uint32* Xr = (const uint32*)Xin + (size_t)node * 32 + q * 4;
                a0.u4 = *(const uint4*)(Xr);
                a1.u4 = *(const uint4*)(Xr + 16);
            }
        }

        f32x4 accT = {0.f, 0.f, 0.f, 0.f};
        f32x4 accR = {0.f, 0.f, 0.f, 0.f};
        accT = __builtin_amdgcn_mfma_f32_16x16x32_bf16(bih[0], a0.s8, accT, 0, 0, 0);
        accT = __builtin_amdgcn_mfma_f32_16x16x32_bf16(bih[1], a1.s8, accT, 0, 0, 0);
        accT = __builtin_amdgcn_mfma_f32_16x16x32_bf16(bil[0], a0.s8, accT, 0, 0, 0);
        accT = __builtin_amdgcn_mfma_f32_16x16x32_bf16(bil[1], a1.s8, accT, 0, 0, 0);
        accR = __builtin_amdgcn_mfma_f32_16x16x32_bf16(brh[0], a0.s8, accR, 0, 0, 0);
        accR = __builtin_amdgcn_mfma_f32_16x16x32_bf16(brh[1], a1.s8, accR, 0, 0, 0);
        accR = __builtin_amdgcn_mfma_f32_16x16x32_bf16(brl[0], a0.s8, accR, 0, 0, 0);
        accR = __builtin_amdgcn_mfma_f32_16x16x32_bf16(brl[1], a1.s8, accR, 0, 0, 0);

        if (node < n) {
            float dv = dinv[node];
            uint2 pT, pR;
            pT.x = pack_bf16(accT[0] * dv, accT[1] * dv);
            pT.y = pack_bf16(accT[2] * dv, accT[3] * dv);
            pR.x = pack_bf16(accR[0] + bias4.x, accR[1] + bias4.y);
            pR.y = pack_bf16(accR[2] + bias4.z, accR[3] + bias4.w);
            size_t o = (size_t)node * 64 + w * 16 + q * 4;
            *(uint2*)&TsU[o] = pT;
            *(uint2*)&RsU[o] = pR;
        }
    }
}

// ---------------- fused gather-propagate + relu: 4 edges per wave, uint2 loads ----------------
__global__ __launch_bounds__(256) void gather_fused(
    const uint2* __restrict__ Ts2, const uint2* __restrict__ Rs2,
    const int* __restrict__ es, const int* __restrict__ nstart,
    const int* __restrict__ ndeg, const float* __restrict__ dinv,
    uint2* __restrict__ Hb2, int n) {
    int c = blockIdx.x * 4 + (threadIdx.x >> 6);
    if (c >= n) return;
    int lane = threadIdx.x & 63;
    int q = lane >> 4;    // edge slot 0..3
    int d4 = lane & 15;   // dim quad
    int deg = ndeg[c];
    int s0 = nstart[c];
    float a0 = 0.f, a1 = 0.f, a2 = 0.f, a3 = 0.f;
    for (int base = 0; base < deg; base += 64) {
        int m = min(deg - base, 64);
        int sid = (lane < m) ? es[s0 + base + lane] : 0;
        for (int j = 0; j < m; j += 16) {
            int e0 = j + q, e1 = j + 4 + q, e2 = j + 8 + q, e3 = j + 12 + q;
            int r0 = __shfl(sid, e0);
            int r1 = __shfl(sid, e1);
            int r2 = __shfl(sid, e2);
            int r3 = __shfl(sid, e3);
            uint2 z = make_uint2(0u, 0u);
            uint2 v0 = (e0 < m) ? Ts2[(size_t)r0 * 16 + d4] : z;
            uint2 v1 = (e1 < m) ? Ts2[(size_t)r1 * 16 + d4] : z;
            uint2 v2 = (e2 < m) ? Ts2[(size_t)r2 * 16 + d4] : z;
            uint2 v3 = (e3 < m) ? Ts2[(size_t)r3 * 16 + d4] : z;
            a0 += bflo(v0.x) + bflo(v1.x) + bflo(v2.x) + bflo(v3.x);
            a1 += bfhi(v0.x) + bfhi(v1.x) + bfhi(v2.x) + bfhi(v3.x);
            a2 += bflo(v0.y) + bflo(v1.y) + bflo(v2.y) + bflo(v3.y);
            a3 += bfhi(v0.y) + bfhi(v1.y) + bfhi(v2.y) + bfhi(v3.y);
        }
    }
    a0 += __shfl_xor(a0, 16); a0 += __shfl_xor(a0, 32);
    a1 += __shfl_xor(a1, 16); a1 += __shfl_xor(a1, 32);
    a2 += __shfl_xor(a2, 16); a2 += __shfl_xor(a2, 32);
    a3 += __shfl_xor(a3, 16); a3 += __shfl_xor(a3, 32);
    if (lane < 16) {
        float dc = dinv[c];
        uint2 ur = Rs2[(size_t)c * 16 + d4];
        float h0 = fmaxf(fmaf(dc, a0, bflo(ur.x)), 0.0f);
        float h1 = fmaxf(fmaf(dc, a1, bfhi(ur.x)), 0.0f);
        float h2 = fmaxf(fmaf(dc, a2, bflo(ur.y)), 0.0f);
        float h3 = fmaxf(fmaf(dc, a3, bfhi(ur.y)), 0.0f);
        Hb2[(size_t)c * 16 + d4] = make_uint2(pack_bf16(h0, h1), pack_bf16(h2, h3));
    }
}

// ---------------- mean-pool over sorted batch + fused FC (last-block-done) ----------------
__global__ __launch_bounds__(256) void pool_kernel(
    const uint32* __restrict__ Hb, const int* __restrict__ batch,
    float* __restrict__ pooled, float* __restrict__ cnt, int n,
    const float* __restrict__ fcw, const float* __restrict__ fcb,
    float* __restrict__ out, int* __restrict__ done, int nblocks) {
    __shared__ float sAcc[64 * 64];
    __shared__ float sCnt[64];
    __shared__ int isLast;
    int tid = threadIdx.x;
    for (int i = tid; i < 4096; i += 256) sAcc[i] = 0.0f;
    if (tid < 64) sCnt[tid] = 0.0f;
    __syncthreads();

    int w = tid >> 6, lane = tid & 63;
    int half = lane >> 5, d2 = lane & 31;
    int s = blockIdx.x * 256 + w * 64;
    int e = min(s + 64, n);
    float a0 = 0.0f, a1 = 0.0f, c = 0.0f;
    int gcur = -1;
    for (int i = s + half; i < e; i += 2) {
        int g = batch[i];
        if (g != gcur) {
            if (gcur >= 0) {
                atomicAdd(&sAcc[gcur * 64 + 2 * d2], a0);
                atomicAdd(&sAcc[gcur * 64 + 2 * d2 + 1], a1);
                if (d2 == 0) atomicAdd(&sCnt[gcur], c);
            }
            gcur = g; a0 = 0.0f; a1 = 0.0f; c = 0.0f;
        }
        uint32 u = Hb[(size_t)i * 32 + d2];
        a0 += bflo(u);
        a1 += bfhi(u);
        c += 1.0f;
    }
    if (gcur >= 0) {
        atomicAdd(&sAcc[gcur * 64 + 2 * d2], a0);
        atomicAdd(&sAcc[gcur * 64 + 2 * d2 + 1], a1);
        if (d2 == 0) atomicAdd(&sCnt[gcur], c);
    }
    __syncthreads();
    for (int i = tid; i < 4096; i += 256) {
        float v = sAcc[i];
        if (v != 0.0f) atomicAdd(&pooled[i], v);
    }
    if (tid < 64) {
        float v = sCnt[tid];
        if (v != 0.0f) atomicAdd(&cnt[tid], v);
    }

    // ---- last block computes FC ----
    __threadfence();
    __syncthreads();
    if (tid == 0) {
        int v = atomicAdd(done, 1);
        isLast = (v == nblocks - 1);
    }
    __syncthreads();
    if (!isLast) return;
    __threadfence();
    // agent-scope loads so we see other XCDs' atomic results
    float pc[64];
    float pl[64];
    for (int idx = tid; idx < 64 * 32; idx += 256) {
        int g = idx >> 5, o = idx & 31;
        float cg = __hip_atomic_load(&cnt[g], __ATOMIC_RELAXED, __HIP_MEMORY_SCOPE_AGENT);
        cg = fmaxf(cg, 1.0f);
        float acc = 0.0f;
#pragma unroll
        for (int k = 0; k < 64; ++k) {
            float pv = __hip_atomic_load(&pooled[g * 64 + k], __ATOMIC_RELAXED, __HIP_MEMORY_SCOPE_AGENT);
            acc = fmaf(pv, fcw[k * 32 + o], acc);
        }
        out[idx] = acc / cg + fcb[o];
    }
    (void)pc; (void)pl;
}

extern "C" void kernel_launch(void* const* d_in, const int* in_sizes, int n_in,
                              void* d_out, int out_size, void* d_ws, size_t ws_size,
                              hipStream_t stream) {
    const float* x       = (const float*)d_in[0];
    const int*   eidx    = (const int*)d_in[1];
    const int*   batch   = (const int*)d_in[2];
    const float* w1_init = (const float*)d_in[3];
    const float* w1_root = (const float*)d_in[4];
    const float* b1      = (const float*)d_in[5];
    const float* w2_init = (const float*)d_in[6];
    const float* w2_root = (const float*)d_in[7];
    const float* b2      = (const float*)d_in[8];
    const float* fc_w    = (const float*)d_in[9];
    const float* fc_b    = (const float*)d_in[10];
    float* out = (float*)d_out;

    const int N = in_sizes[0] / 64;
    const int E = in_sizes[1] / 2;
    const int* row = eidx;
    const int* col = eidx + E;

    const int B = (N + NB - 1) / NB;  // 391 buckets

    // workspace (4-byte units):
    // bpack(B*CAP) | es(B*CAP) | [zeroed: bcnt(MAXB) | pooled(4096) | cnt(64) | done(16)]
    // | nstart(N) | ndeg(N) | dinv(N) | wt(16384) | Ts(N*32) | Rs(N*32) | Hb(N*32)
    uint32* bpack = (uint32*)d_ws;
    int*   es     = (int*)(bpack + (size_t)B * CAP);
    int*   bcnt   = es + (size_t)B * CAP;
    float* pooled = (float*)(bcnt + MAXB);
    float* cnt    = pooled + 64 * 64;
    int*   done   = (int*)(cnt + 64);
    int*   nstart = done + 16;
    int*   ndeg   = nstart + N;
    float* dinv   = (float*)(ndeg + N);
    uint32* wtU   = (uint32*)(dinv + N);            // 16384 uints (64 KB)
    uint32* Ts    = wtU + 16384;                    // N*32
    uint32* Rs    = Ts + (size_t)N * 32;            // N*32
    uint32* Hb    = Rs + (size_t)N * 32;            // N*32
    ushort16* wt  = (ushort16*)wtU;

    hipMemsetAsync(bcnt, 0, (size_t)(MAXB + 64 * 64 + 64 + 16) * sizeof(int), stream);

    // bucket + fused weight prep (first 128 blocks), then per-bucket CSR
    const int EB = (E + P1_CHUNK - 1) / P1_CHUNK;
    bucket_kernel<<<128 + EB, 256, 0, stream>>>(row, col, bpack, (int*)bcnt, E,
                                                w1_init, w1_root, w2_init, w2_root, wt);
    csr_kernel<<<B, 1024, 0, stream>>>(bpack, bcnt, es, nstart, ndeg, dinv, N);

    // layer 1 (f32 input); wt = mats 0..3
    gemm_mfma<<<(N + 63) / 64, 256, 0, stream>>>(x, wt, b1, dinv,
                                                 (ushort16*)Ts, (ushort16*)Rs, N, 1);
    gather_fused<<<(N + 3) / 4, 256, 0, stream>>>((const uint2*)Ts, (const uint2*)Rs,
                                                  es, nstart, ndeg, dinv, (uint2*)Hb, N);

    // layer 2 (bf16 input); wt + 4*4096 ushorts = mats 4..7
    gemm_mfma<<<(N + 63) / 64, 256, 0, stream>>>(Hb, wt + (size_t)4 * 4096, b2, dinv,
                                                 (ushort16*)Ts, (ushort16*)Rs, N, 0);
    gather_fused<<<(N + 3) / 4, 256, 0, stream>>>((const uint2*)Ts, (const uint2*)Rs,
                                                  es, nstart, ndeg, dinv, (uint2*)Hb, N);

    // pool + fused FC (last-block-done)
    const int PB = (N + 255) / 256;
    pool_kernel<<<PB, 256, 0, stream>>>(Hb, batch, pooled, cnt, N,
                                        fc_w, fc_b, out, done, PB);
}

// Round 6
// 288.025 us; speedup vs baseline: 2.4330x; 1.1472x over previous
//
#include <hip/hip_runtime.h>
#include <hip/hip_bf16.h>

// ARMANet: 2x ARMAConv(K=1,T=1) + global mean pool + FC
// N=100000 nodes, E=1600000 edges, IN=HID=64, OUT=32, G=64 graphs.
// R25 = R20 proven components + pool parallelism fix.
//  - R24 verdicts: pool+FC fusion regressed (per-block threadfence = L2
//    writeback x391 + agent-scope FC loads; 68us steady + 30ms outlier);
//    LDS-free gemm ~10us/dispatch slower (4x wave-redundant X reads).
//    Both reverted to R20 form.
//  - pool_kernel: R24 showed it latency-bound (8% occupancy, VALU 1.5%).
//    Fix: 64 nodes/block (grid 391->1563, 4x TLP). Same algorithm/numerics.
//  - bucket(+wprep fused), csr, LDS-staged MFMA gemm, pull gather, final_fc:
//    exact R20/R14 forms (proven 293-294us configuration).

#define NB 256
#define CAP 5120
#define MAXB 400
#define P1_CHUNK 2048

typedef unsigned int uint32;
typedef unsigned short ushort16;
typedef __attribute__((ext_vector_type(8))) short short8;   // 8 bf16 (4 VGPRs)
typedef __attribute__((ext_vector_type(4))) float f32x4;    // MFMA C/D

__device__ inline uint32 bf16rn(float f) {
    uint32 u = __float_as_uint(f);
    uint32 r = ((u >> 16) & 1u) + 0x7FFFu;
    return (u + r) >> 16;
}
__device__ inline uint32 pack_bf16(float a, float b) {
    return bf16rn(a) | (bf16rn(b) << 16);
}
__device__ inline float bflo(uint32 u) { return __uint_as_float(u << 16); }
__device__ inline float bfhi(uint32 u) { return __uint_as_float(u & 0xFFFF0000u); }

// ---------------- stage 1: bucket edges by destination (+ fused weight prep) ----------------
// blocks [0,128): weights -> transposed split-bf16 table wt[m][d*64+k]
//   m: 0=init_hi 1=init_lo 2=root_hi 3=root_lo (x2 layers -> 8 mats).
// blocks [128,...): 2048-edge chunk bucketing by col>>8.
__global__ __launch_bounds__(256) void bucket_kernel(
    const int* __restrict__ row, const int* __restrict__ col,
    uint32* __restrict__ bpack, int* __restrict__ bcnt, int E,
    const float* __restrict__ W1i, const float* __restrict__ W1r,
    const float* __restrict__ W2i, const float* __restrict__ W2r,
    ushort16* __restrict__ wt) {
    __shared__ int hist[MAXB];
    __shared__ int ofs[MAXB];
    __shared__ int cur[MAXB];
    __shared__ int gbase[MAXB];
    __shared__ int s[256];
    __shared__ uint32 stage[P1_CHUNK];
    __shared__ unsigned short stage_bk[P1_CHUNK];

    int t = threadIdx.x;

    if (blockIdx.x < 128) {
        // ---- wprep role ----
        int idx = blockIdx.x * 256 + t;     // 8*4096 items over 128 blocks
        int m = idx >> 12;
        int r = idx & 4095;
        int d = r >> 6, k = r & 63;
        const float* W = (m < 2) ? W1i : (m < 4) ? W1r : (m < 6) ? W2i : W2r;
        float v = W[k * 64 + d];
        uint32 hi = bf16rn(v);
        uint32 outv;
        if (m & 1) {
            float hf = __uint_as_float(hi << 16);
            outv = bf16rn(v - hf);
        } else {
            outv = hi;
        }
        wt[(size_t)m * 4096 + d * 64 + k] = (unsigned short)outv;
        return;
    }

    for (int i = t; i < MAXB; i += 256) hist[i] = 0;
    __syncthreads();

    int e0 = (blockIdx.x - 128) * P1_CHUNK;
    int cntE = min(E - e0, P1_CHUNK);

    for (int i = t; i < cntE; i += 256) {
        int c = col[e0 + i];
        atomicAdd(&hist[c >> 8], 1);
    }
    __syncthreads();

    int i2 = 2 * t;
    int a = (i2 < MAXB) ? hist[i2] : 0;
    int b = (i2 + 1 < MAXB) ? hist[i2 + 1] : 0;
    s[t] = a + b;
    __syncthreads();
    for (int off = 1; off < 256; off <<= 1) {
        int x = (t >= off) ? s[t - off] : 0;
        __syncthreads();
        s[t] += x;
        __syncthreads();
    }
    int excl = (t > 0) ? s[t - 1] : 0;
    if (i2 < MAXB) ofs[i2] = excl;
    if (i2 + 1 < MAXB) ofs[i2 + 1] = excl + a;
    __syncthreads();

    for (int i = t; i < MAXB; i += 256) {
        cur[i] = ofs[i];
        gbase[i] = hist[i] ? atomicAdd(&bcnt[i], hist[i]) : 0;
    }
    __syncthreads();

    for (int i = t; i < cntE; i += 256) {
        int c = col[e0 + i];
        int r = row[e0 + i];
        int bk = c >> 8;
        int k = atomicAdd(&cur[bk], 1);
        stage[k] = ((uint32)(c & 255) << 24) | (uint32)r;
        stage_bk[k] = (unsigned short)bk;
    }
    __syncthreads();

    for (int i = t; i < cntE; i += 256) {
        uint32 pk = stage[i];
        int bk = stage_bk[i];
        int gd = gbase[bk] + (i - ofs[bk]);
        if (gd < CAP) bpack[(size_t)bk * CAP + gd] = pk;
    }
}

// ---------------- stage 2: per-bucket counting sort -> CSR + dinv ----------------
__global__ __launch_bounds__(1024) void csr_kernel(
    const uint32* __restrict__ bpack, const int* __restrict__ bcnt,
    int* __restrict__ es, int* __restrict__ nstart, int* __restrict__ ndeg,
    float* __restrict__ dinv, int n) {
    __shared__ uint32 sbp[CAP];   // 20 KB
    __shared__ int h[NB];
    __shared__ int s[NB];
    __shared__ int cur[NB];
    int b = blockIdx.x, t = threadIdx.x;
    if (t < NB) h[t] = 0;
    __syncthreads();
    int cnt = min(bcnt[b], CAP);
    size_t base = (size_t)b * CAP;
    for (int i = t; i < cnt; i += 1024) {
        uint32 pk = bpack[base + i];
        sbp[i] = pk;
        atomicAdd(&h[pk >> 24], 1);
    }
    __syncthreads();
    if (t < NB) s[t] = h[t];
    __syncthreads();
    for (int off = 1; off < NB; off <<= 1) {
        int x = 0;
        if (t < NB && t >= off) x = s[t - off];
        __syncthreads();
        if (t < NB) s[t] += x;
        __syncthreads();
    }
    if (t < NB) {
        int myofs = s[t] - h[t];
        cur[t] = myofs;
        int node = b * NB + t;
        if (node < n) {
            nstart[node] = (int)base + myofs;
            ndeg[node] = h[t];
            dinv[node] = h[t] ? rsqrtf((float)h[t]) : 0.0f;
        }
    }
    __syncthreads();
    for (int i = t; i < cnt; i += 1024) {
        uint32 pk = sbp[i];
        int cl = (int)(pk >> 24);
        int p = atomicAdd(&cur[cl], 1);
        es[base + p] = (int)(pk & 0xFFFFFFu);
    }
}

// ---------------- MFMA dual GEMM (fused f32->bf16 X staging) ----------------
// Ts = bf16(dinv .* (X@Winit)), Rs = bf16(X@Wroot + bias).
// X: f32 (xf32=1, layer 1) or packed bf16 uint rows (xf32=0, layer 2).
// Swapped MFMA operands -> transposed C tile: each thread holds 4 consecutive
// dims of ONE node -> packed uint2 stores, coalesced per-node dinv loads.
__global__ __launch_bounds__(256) void gemm_mfma(
    const void* __restrict__ Xin,
    const ushort16* __restrict__ wt4,
    const float* __restrict__ bias, const float* __restrict__ dinv,
    ushort16* __restrict__ Ts, ushort16* __restrict__ Rs, int n, int xf32) {
    __shared__ unsigned short sXs[64 * 72];   // 9216 B, row stride 72 bf16
    int t = threadIdx.x;
    int node0 = blockIdx.x * 64;

    if (xf32) {
        const float* X = (const float*)Xin;
        for (int i = t; i < 1024; i += 256) {
            int r = i >> 4, c4 = (i & 15) * 4;
            int node = node0 + r;
            float4 v = make_float4(0.f, 0.f, 0.f, 0.f);
            if (node < n) v = *(const float4*)&X[(size_t)node * 64 + c4];
            *(uint32*)&sXs[r * 72 + c4] = pack_bf16(v.x, v.y);
            *(uint32*)&sXs[r * 72 + c4 + 2] = pack_bf16(v.z, v.w);
        }
    } else {
        const uint32* Xb2 = (const uint32*)Xin;
        for (int i = t; i < 512; i += 256) {
            int r = i >> 3, kg = i & 7;
            int node = node0 + r;
            uint4 v = make_uint4(0u, 0u, 0u, 0u);
            if (node < n) v = *(const uint4*)&Xb2[(size_t)node * 32 + kg * 4];
            *(uint4*)&sXs[r * 72 + kg * 8] = v;
        }
    }

    int w = t >> 6;
    int lane = t & 63;
    int q = lane >> 4;
    int col = lane & 15;
    int dim = w * 16 + col;

    short8 bih[2], bil[2], brh[2], brl[2];
#pragma unroll
    for (int kh = 0; kh < 2; ++kh) {
        size_t o = (size_t)dim * 64 + kh * 32 + q * 8;
        bih[kh] = *(const short8*)&wt4[0 * 4096 + o];
        bil[kh] = *(const short8*)&wt4[1 * 4096 + o];
        brh[kh] = *(const short8*)&wt4[2 * 4096 + o];
        brl[kh] = *(const short8*)&wt4[3 * 4096 + o];
    }
    float4 bias4 = *(const float4*)&bias[w * 16 + q * 4];
    __syncthreads();

    unsigned short* TsU = (unsigned short*)Ts;
    unsigned short* RsU = (unsigned short*)Rs;

#pragma unroll
    for (int mt = 0; mt < 4; ++mt) {
        int rbase = mt * 16 + col;
        short8 a0 = *(const short8*)&sXs[rbase * 72 + q * 8];
        short8 a1 = *(const short8*)&sXs[rbase * 72 + 32 + q * 8];
        f32x4 accT = {0.f, 0.f, 0.f, 0.f};
        f32x4 accR = {0.f, 0.f, 0.f, 0.f};
        accT = __builtin_amdgcn_mfma_f32_16x16x32_bf16(bih[0], a0, accT, 0, 0, 0);
        accT = __builtin_amdgcn_mfma_f32_16x16x32_bf16(bih[1], a1, accT, 0, 0, 0);
        accT = __builtin_amdgcn_mfma_f32_16x16x32_bf16(bil[0], a0, accT, 0, 0, 0);
        accT = __builtin_amdgcn_mfma_f32_16x16x32_bf16(bil[1], a1, accT, 0, 0, 0);
        accR = __builtin_amdgcn_mfma_f32_16x16x32_bf16(brh[0], a0, accR, 0, 0, 0);
        accR = __builtin_amdgcn_mfma_f32_16x16x32_bf16(brh[1], a1, accR, 0, 0, 0);
        accR = __builtin_amdgcn_mfma_f32_16x16x32_bf16(brl[0], a0, accR, 0, 0, 0);
        accR = __builtin_amdgcn_mfma_f32_16x16x32_bf16(brl[1], a1, accR, 0, 0, 0);

        int node = node0 + mt * 16 + col;
        if (node < n) {
            float dv = dinv[node];
            uint2 pT, pR;
            pT.x = pack_bf16(accT[0] * dv, accT[1] * dv);
            pT.y = pack_bf16(accT[2] * dv, accT[3] * dv);
            pR.x = pack_bf16(accR[0] + bias4.x, accR[1] + bias4.y);
            pR.y = pack_bf16(accR[2] + bias4.z, accR[3] + bias4.w);
            size_t o = (size_t)node * 64 + w * 16 + q * 4;
            *(uint2*)&TsU[o] = pT;
            *(uint2*)&RsU[o] = pR;
        }
    }
}

// ---------------- fused gather-propagate + relu: 4 edges per wave, uint2 loads ----------------
__global__ __launch_bounds__(256) void gather_fused(
    const uint2* __restrict__ Ts2, const uint2* __restrict__ Rs2,
    const int* __restrict__ es, const int* __restrict__ nstart,
    const int* __restrict__ ndeg, const float* __restrict__ dinv,
    uint2* __restrict__ Hb2, int n) {
    int c = blockIdx.x * 4 + (threadIdx.x >> 6);
    if (c >= n) return;
    int lane = threadIdx.x & 63;
    int q = lane >> 4;    // edge slot 0..3
    int d4 = lane & 15;   // dim quad
    int deg = ndeg[c];
    int s0 = nstart[c];
    float a0 = 0.f, a1 = 0.f, a2 = 0.f, a3 = 0.f;
    for (int base = 0; base < deg; base += 64) {
        int m = min(deg - base, 64);
        int sid = (lane < m) ? es[s0 + base + lane] : 0;
        for (int j = 0; j < m; j += 16) {
            int e0 = j + q, e1 = j + 4 + q, e2 = j + 8 + q, e3 = j + 12 + q;
            int r0 = __shfl(sid, e0);
            int r1 = __shfl(sid, e1);
            int r2 = __shfl(sid, e2);
            int r3 = __shfl(sid, e3);
            uint2 z = make_uint2(0u, 0u);
            uint2 v0 = (e0 < m) ? Ts2[(size_t)r0 * 16 + d4] : z;
            uint2 v1 = (e1 < m) ? Ts2[(size_t)r1 * 16 + d4] : z;
            uint2 v2 = (e2 < m) ? Ts2[(size_t)r2 * 16 + d4] : z;
            uint2 v3 = (e3 < m) ? Ts2[(size_t)r3 * 16 + d4] : z;
            a0 += bflo(v0.x) + bflo(v1.x) + bflo(v2.x) + bflo(v3.x);
            a1 += bfhi(v0.x) + bfhi(v1.x) + bfhi(v2.x) + bfhi(v3.x);
            a2 += bflo(v0.y) + bflo(v1.y) + bflo(v2.y) + bflo(v3.y);
            a3 += bfhi(v0.y) + bfhi(v1.y) + bfhi(v2.y) + bfhi(v3.y);
        }
    }
    a0 += __shfl_xor(a0, 16); a0 += __shfl_xor(a0, 32);
    a1 += __shfl_xor(a1, 16); a1 += __shfl_xor(a1, 32);
    a2 += __shfl_xor(a2, 16); a2 += __shfl_xor(a2, 32);
    a3 += __shfl_xor(a3, 16); a3 += __shfl_xor(a3, 32);
    if (lane < 16) {
        float dc = dinv[c];
        uint2 ur = Rs2[(size_t)c * 16 + d4];
        float h0 = fmaxf(fmaf(dc, a0, bflo(ur.x)), 0.0f);
        float h1 = fmaxf(fmaf(dc, a1, bfhi(ur.x)), 0.0f);
        float h2 = fmaxf(fmaf(dc, a2, bflo(ur.y)), 0.0f);
        float h3 = fmaxf(fmaf(dc, a3, bfhi(ur.y)), 0.0f);
        Hb2[(size_t)c * 16 + d4] = make_uint2(pack_bf16(h0, h1), pack_bf16(h2, h3));
    }
}

// ---------------- mean-pool over sorted batch: 64 nodes/block (4x TLP vs R20) ----------------
__global__ __launch_bounds__(256) void pool_kernel(
    const uint32* __restrict__ Hb, const int* __restrict__ batch,
    float* __restrict__ pooled, float* __restrict__ cnt, int n) {
    __shared__ float sAcc[64 * 64];
    __shared__ float sCnt[64];
    int tid = threadIdx.x;
    for (int i = tid; i < 4096; i += 256) sAcc[i] = 0.0f;
    if (tid < 64) sCnt[tid] = 0.0f;
    __syncthreads();

    int w = tid >> 6, lane = tid & 63;
    int half = lane >> 5, d2 = lane & 31;
    int s = blockIdx.x * 64 + w * 16;    // wave covers 16 nodes (was 64)
    int e = min(s + 16, n);
    float a0 = 0.0f, a1 = 0.0f, c = 0.0f;
    int gcur = -1;
    for (int i = s + half; i < e; i += 2) {
        int g = batch[i];
        if (g != gcur) {
            if (gcur >= 0) {
                atomicAdd(&sAcc[gcur * 64 + 2 * d2], a0);
                atomicAdd(&sAcc[gcur * 64 + 2 * d2 + 1], a1);
                if (d2 == 0) atomicAdd(&sCnt[gcur], c);
            }
            gcur = g; a0 = 0.0f; a1 = 0.0f; c = 0.0f;
        }
        uint32 u = Hb[(size_t)i * 32 + d2];
        a0 += bflo(u);
        a1 += bfhi(u);
        c += 1.0f;
    }
    if (gcur >= 0) {
        atomicAdd(&sAcc[gcur * 64 + 2 * d2], a0);
        atomicAdd(&sAcc[gcur * 64 + 2 * d2 + 1], a1);
        if (d2 == 0) atomicAdd(&sCnt[gcur], c);
    }
    __syncthreads();
    for (int i = tid; i < 4096; i += 256) {
        float v = sAcc[i];
        if (v != 0.0f) atomicAdd(&pooled[i], v);
    }
    if (tid < 64) {
        float v = sCnt[tid];
        if (v != 0.0f) atomicAdd(&cnt[tid], v);
    }
}

// ---------------- out[g,o] = (pooled[g,:]/max(cnt,1)) @ fcw + fcb ----------------
__global__ void final_fc(const float* __restrict__ pooled, const float* __restrict__ cnt,
                         const float* __restrict__ fcw, const float* __restrict__ fcb,
                         float* __restrict__ out) {
    int idx = blockIdx.x * 256 + threadIdx.x;
    if (idx >= 64 * 32) return;
    int g = idx >> 5, o = idx & 31;
    float c = fmaxf(cnt[g], 1.0f);
    float acc = 0.0f;
#pragma unroll
    for (int k = 0; k < 64; ++k) acc = fmaf(pooled[g * 64 + k], fcw[k * 32 + o], acc);
    out[idx] = acc / c + fcb[o];
}

extern "C" void kernel_launch(void* const* d_in, const int* in_sizes, int n_in,
                              void* d_out, int out_size, void* d_ws, size_t ws_size,
                              hipStream_t stream) {
    const float* x       = (const float*)d_in[0];
    const int*   eidx    = (const int*)d_in[1];
    const int*   batch   = (const int*)d_in[2];
    const float* w1_init = (const float*)d_in[3];
    const float* w1_root = (const float*)d_in[4];
    const float* b1      = (const float*)d_in[5];
    const float* w2_init = (const float*)d_in[6];
    const float* w2_root = (const float*)d_in[7];
    const float* b2      = (const float*)d_in[8];
    const float* fc_w    = (const float*)d_in[9];
    const float* fc_b    = (const float*)d_in[10];
    float* out = (float*)d_out;

    const int N = in_sizes[0] / 64;
    const int E = in_sizes[1] / 2;
    const int* row = eidx;
    const int* col = eidx + E;

    const int B = (N + NB - 1) / NB;  // 391 buckets

    // workspace (4-byte units, 16B-aligned chunks):
    // bpack(B*CAP) | es(B*CAP) | [zeroed: bcnt(MAXB) | pooled(4096) | cnt(64)]
    // | nstart(N) | ndeg(N) | dinv(N) | wt(16384) | Ts(N*32) | Rs(N*32) | Hb(N*32)
    uint32* bpack = (uint32*)d_ws;
    int*   es     = (int*)(bpack + (size_t)B * CAP);
    int*   bcnt   = es + (size_t)B * CAP;
    float* pooled = (float*)(bcnt + MAXB);
    float* cnt    = pooled + 64 * 64;
    int*   nstart = (int*)(cnt + 64);
    int*   ndeg   = nstart + N;
    float* dinv   = (float*)(ndeg + N);
    uint32* wtU   = (uint32*)(dinv + N);            // 16384 uints (64 KB)
    uint32* Ts    = wtU + 16384;                    // N*32
    uint32* Rs    = Ts + (size_t)N * 32;            // N*32
    uint32* Hb    = Rs + (size_t)N * 32;            // N*32
    ushort16* wt  = (ushort16*)wtU;

    hipMemsetAsync(bcnt, 0, (size_t)(MAXB + 64 * 64 + 64) * sizeof(int), stream);

    // bucket + fused weight prep (first 128 blocks), then per-bucket CSR
    const int EB = (E + P1_CHUNK - 1) / P1_CHUNK;
    bucket_kernel<<<128 + EB, 256, 0, stream>>>(row, col, bpack, bcnt, E,
                                                w1_init, w1_root, w2_init, w2_root, wt);
    csr_kernel<<<B, 1024, 0, stream>>>(bpack, bcnt, es, nstart, ndeg, dinv, N);

    // layer 1 (f32 input); wt = mats 0..3
    gemm_mfma<<<(N + 63) / 64, 256, 0, stream>>>(x, wt, b1, dinv,
                                                 (ushort16*)Ts, (ushort16*)Rs, N, 1);
    gather_fused<<<(N + 3) / 4, 256, 0, stream>>>((const uint2*)Ts, (const uint2*)Rs,
                                                  es, nstart, ndeg, dinv, (uint2*)Hb, N);

    // layer 2 (bf16 input); wt + 4*4096 ushorts = mats 4..7
    gemm_mfma<<<(N + 63) / 64, 256, 0, stream>>>(Hb, wt + (size_t)4 * 4096, b2, dinv,
                                                 (ushort16*)Ts, (ushort16*)Rs, N, 0);
    gather_fused<<<(N + 3) / 4, 256, 0, stream>>>((const uint2*)Ts, (const uint2*)Rs,
                                                  es, nstart, ndeg, dinv, (uint2*)Hb, N);

    // pool (64 nodes/block) + FC
    pool_kernel<<<(N + 63) / 64, 256, 0, stream>>>(Hb, batch, pooled, cnt, N);
    final_fc<<<(64 * 32 + 255) / 256, 256, 0, stream>>>(pooled, cnt, fc_w, fc_b, out);
}

// Round 7
// 281.988 us; speedup vs baseline: 2.4851x; 1.0214x over previous
//
#include <hip/hip_runtime.h>
#include <hip/hip_bf16.h>

// ARMANet: 2x ARMAConv(K=1,T=1) + global mean pool + FC
// N=100000 nodes, E=1600000 edges, IN=HID=64, OUT=32, G=64 graphs.
// R26 = R25 + dependency-aware fusion (bit-identical numerics).
//  Accounting (R19-R25 invariant): gathers 106us + ~182us residual across 7
//  small dispatches -> boundaries + standalone-kernel round-trips are the
//  remaining lever. Fusions that need NO rounding change:
//  - csr_gemm: csr bucket == 256 nodes == 4 gemm tiles; block recomputes
//    dinv from LDS h[] (same rsqrtf) and runs layer-1 MFMA after the
//    scatter (LDS union sbp/scan <-> staged-X, 37KB).
//  - gather_gemm: block = 64 dests (4 waves x 16 rounds, inner loop
//    identical); epilogue writes the same packed-bf16 bits to LDS; then the
//    original 256-thr gemm body (layer 2) reads LDS. Layer-1 Hb never hits
//    memory (-25.6MB traffic, -1 dispatch).
//  - layer-2 Ts/Rs -> separate buffers (no race with layer-1 reads);
//    gather2 writes into the dead Ts1 region; pool reads it.
//  9 dispatches -> 7. Pull gather inner loop, bucket(+wprep), pool(64/blk),
//  fc all unchanged from R25.

#define NB 256
#define CAP 5120
#define MAXB 400
#define P1_CHUNK 2048

typedef unsigned int uint32;
typedef unsigned short ushort16;
typedef __attribute__((ext_vector_type(8))) short short8;   // 8 bf16 (4 VGPRs)
typedef __attribute__((ext_vector_type(4))) float f32x4;    // MFMA C/D

__device__ inline uint32 bf16rn(float f) {
    uint32 u = __float_as_uint(f);
    uint32 r = ((u >> 16) & 1u) + 0x7FFFu;
    return (u + r) >> 16;
}
__device__ inline uint32 pack_bf16(float a, float b) {
    return bf16rn(a) | (bf16rn(b) << 16);
}
__device__ inline float bflo(uint32 u) { return __uint_as_float(u << 16); }
__device__ inline float bfhi(uint32 u) { return __uint_as_float(u & 0xFFFF0000u); }

// ---------------- stage 1: bucket edges by destination (+ fused weight prep) ----------------
__global__ __launch_bounds__(256) void bucket_kernel(
    const int* __restrict__ row, const int* __restrict__ col,
    uint32* __restrict__ bpack, int* __restrict__ bcnt, int E,
    const float* __restrict__ W1i, const float* __restrict__ W1r,
    const float* __restrict__ W2i, const float* __restrict__ W2r,
    ushort16* __restrict__ wt) {
    __shared__ int hist[MAXB];
    __shared__ int ofs[MAXB];
    __shared__ int cur[MAXB];
    __shared__ int gbase[MAXB];
    __shared__ int s[256];
    __shared__ uint32 stage[P1_CHUNK];
    __shared__ unsigned short stage_bk[P1_CHUNK];

    int t = threadIdx.x;

    if (blockIdx.x < 128) {
        // ---- wprep role ----
        int idx = blockIdx.x * 256 + t;     // 8*4096 items over 128 blocks
        int m = idx >> 12;
        int r = idx & 4095;
        int d = r >> 6, k = r & 63;
        const float* W = (m < 2) ? W1i : (m < 4) ? W1r : (m < 6) ? W2i : W2r;
        float v = W[k * 64 + d];
        uint32 hi = bf16rn(v);
        uint32 outv;
        if (m & 1) {
            float hf = __uint_as_float(hi << 16);
            outv = bf16rn(v - hf);
        } else {
            outv = hi;
        }
        wt[(size_t)m * 4096 + d * 64 + k] = (unsigned short)outv;
        return;
    }

    for (int i = t; i < MAXB; i += 256) hist[i] = 0;
    __syncthreads();

    int e0 = (blockIdx.x - 128) * P1_CHUNK;
    int cntE = min(E - e0, P1_CHUNK);

    for (int i = t; i < cntE; i += 256) {
        int c = col[e0 + i];
        atomicAdd(&hist[c >> 8], 1);
    }
    __syncthreads();

    int i2 = 2 * t;
    int a = (i2 < MAXB) ? hist[i2] : 0;
    int b = (i2 + 1 < MAXB) ? hist[i2 + 1] : 0;
    s[t] = a + b;
    __syncthreads();
    for (int off = 1; off < 256; off <<= 1) {
        int x = (t >= off) ? s[t - off] : 0;
        __syncthreads();
        s[t] += x;
        __syncthreads();
    }
    int excl = (t > 0) ? s[t - 1] : 0;
    if (i2 < MAXB) ofs[i2] = excl;
    if (i2 + 1 < MAXB) ofs[i2 + 1] = excl + a;
    __syncthreads();

    for (int i = t; i < MAXB; i += 256) {
        cur[i] = ofs[i];
        gbase[i] = hist[i] ? atomicAdd(&bcnt[i], hist[i]) : 0;
    }
    __syncthreads();

    for (int i = t; i < cntE; i += 256) {
        int c = col[e0 + i];
        int r = row[e0 + i];
        int bk = c >> 8;
        int k = atomicAdd(&cur[bk], 1);
        stage[k] = ((uint32)(c & 255) << 24) | (uint32)r;
        stage_bk[k] = (unsigned short)bk;
    }
    __syncthreads();

    for (int i = t; i < cntE; i += 256) {
        uint32 pk = stage[i];
        int bk = stage_bk[i];
        int gd = gbase[bk] + (i - ofs[bk]);
        if (gd < CAP) bpack[(size_t)bk * CAP + gd] = pk;
    }
}

// ---------------- stage 2: per-bucket counting sort -> CSR + dinv, FUSED layer-1 gemm ----------------
// Phase A: exact R25 csr body (sbp/scan in LDS union). Phase B: same block
// stages X (f32->bf16) for its 256 nodes = 4 tiles and runs the MFMA dual
// GEMM; dinv recomputed from LDS h[] (identical rsqrtf path).
__global__ __launch_bounds__(1024) void csr_gemm(
    const uint32* __restrict__ bpack, const int* __restrict__ bcnt,
    int* __restrict__ es, int* __restrict__ nstart, int* __restrict__ ndeg,
    float* __restrict__ dinv,
    const float* __restrict__ X, const ushort16* __restrict__ wt4,
    const float* __restrict__ bias,
    ushort16* __restrict__ Ts, ushort16* __restrict__ Rs, int n) {
    __shared__ int h[NB];
    __shared__ alignas(16) unsigned char uni[36864];   // max(csr 22.5KB, sXs 36.9KB)
    uint32* sbp = (uint32*)uni;                         // [CAP]   20480 B
    int* s      = (int*)(uni + 20480);                  // [NB]
    int* cur    = (int*)(uni + 21504);                  // [NB]
    unsigned short* sXs = (unsigned short*)uni;         // [4][64*72] phase B

    int b = blockIdx.x, t = threadIdx.x;
    if (t < NB) h[t] = 0;
    __syncthreads();
    int cnt = min(bcnt[b], CAP);
    size_t base = (size_t)b * CAP;
    for (int i = t; i < cnt; i += 1024) {
        uint32 pk = bpack[base + i];
        sbp[i] = pk;
        atomicAdd(&h[pk >> 24], 1);
    }
    __syncthreads();
    if (t < NB) s[t] = h[t];
    __syncthreads();
    for (int off = 1; off < NB; off <<= 1) {
        int x = 0;
        if (t < NB && t >= off) x = s[t - off];
        __syncthreads();
        if (t < NB) s[t] += x;
        __syncthreads();
    }
    if (t < NB) {
        int myofs = s[t] - h[t];
        cur[t] = myofs;
        int node = b * NB + t;
        if (node < n) {
            nstart[node] = (int)base + myofs;
            ndeg[node] = h[t];
            dinv[node] = h[t] ? rsqrtf((float)h[t]) : 0.0f;
        }
    }
    __syncthreads();
    for (int i = t; i < cnt; i += 1024) {
        uint32 pk = sbp[i];
        int cl = (int)(pk >> 24);
        int p = atomicAdd(&cur[cl], 1);
        es[base + p] = (int)(pk & 0xFFFFFFu);
    }
    __syncthreads();   // sbp fully consumed; union switches to sXs

    // ---- Phase B: stage X (4 tiles x [64 rows x 72 bf16]) ----
    for (int i = t; i < 4096; i += 1024) {
        int tile = i >> 10, j = i & 1023;
        int r = j >> 4, c4 = (j & 15) * 4;
        int node = b * NB + tile * 64 + r;
        float4 v = make_float4(0.f, 0.f, 0.f, 0.f);
        if (node < n) v = *(const float4*)&X[(size_t)node * 64 + c4];
        *(uint32*)&sXs[tile * 4608 + r * 72 + c4] = pack_bf16(v.x, v.y);
        *(uint32*)&sXs[tile * 4608 + r * 72 + c4 + 2] = pack_bf16(v.z, v.w);
    }
    __syncthreads();

    // ---- MFMA: wave wv -> tile wv>>2, dim-quadrant wv&3 (orig 256-thr map) ----
    int wv = t >> 6, lane = t & 63;
    int tile = wv >> 2, wq = wv & 3;
    int q = lane >> 4, colx = lane & 15;
    int dim = wq * 16 + colx;

    short8 bih[2], bil[2], brh[2], brl[2];
#pragma unroll
    for (int kh = 0; kh < 2; ++kh) {
        size_t o = (size_t)dim * 64 + kh * 32 + q * 8;
        bih[kh] = *(const short8*)&wt4[0 * 4096 + o];
        bil[kh] = *(const short8*)&wt4[1 * 4096 + o];
        brh[kh] = *(const short8*)&wt4[2 * 4096 + o];
        brl[kh] = *(const short8*)&wt4[3 * 4096 + o];
    }
    float4 bias4 = *(const float4*)&bias[wq * 16 + q * 4];

    unsigned short* TsU = (unsigned short*)Ts;
    unsigned short* RsU = (unsigned short*)Rs;

#pragma unroll
    for (int mt = 0; mt < 4; ++mt) {
        int rbase = mt * 16 + colx;
        short8 a0 = *(const short8*)&sXs[tile * 4608 + rbase * 72 + q * 8];
        short8 a1 = *(const short8*)&sXs[tile * 4608 + rbase * 72 + 32 + q * 8];
        f32x4 accT = {0.f, 0.f, 0.f, 0.f};
        f32x4 accR = {0.f, 0.f, 0.f, 0.f};
        accT = __builtin_amdgcn_mfma_f32_16x16x32_bf16(bih[0], a0, accT, 0, 0, 0);
        accT = __builtin_amdgcn_mfma_f32_16x16x32_bf16(bih[1], a1, accT, 0, 0, 0);
        accT = __builtin_amdgcn_mfma_f32_16x16x32_bf16(bil[0], a0, accT, 0, 0, 0);
        accT = __builtin_amdgcn_mfma_f32_16x16x32_bf16(bil[1], a1, accT, 0, 0, 0);
        accR = __builtin_amdgcn_mfma_f32_16x16x32_bf16(brh[0], a0, accR, 0, 0, 0);
        accR = __builtin_amdgcn_mfma_f32_16x16x32_bf16(brh[1], a1, accR, 0, 0, 0);
        accR = __builtin_amdgcn_mfma_f32_16x16x32_bf16(brl[0], a0, accR, 0, 0, 0);
        accR = __builtin_amdgcn_mfma_f32_16x16x32_bf16(brl[1], a1, accR, 0, 0, 0);

        int li = tile * 64 + mt * 16 + colx;
        int node = b * NB + li;
        if (node < n) {
            int dg = h[li];
            float dv = dg ? rsqrtf((float)dg) : 0.0f;   // identical to csr dinv
            uint2 pT, pR;
            pT.x = pack_bf16(accT[0] * dv, accT[1] * dv);
            pT.y = pack_bf16(accT[2] * dv, accT[3] * dv);
            pR.x = pack_bf16(accR[0] + bias4.x, accR[1] + bias4.y);
            pR.y = pack_bf16(accR[2] + bias4.z, accR[3] + bias4.w);
            size_t o = (size_t)node * 64 + wq * 16 + q * 4;
            *(uint2*)&TsU[o] = pT;
            *(uint2*)&RsU[o] = pR;
        }
    }
}

// ---------------- gather1 + layer-2 gemm fused ----------------
// Block = 64 dests; wave w handles dests [w*16, w*16+16) sequentially with
// the UNCHANGED pull inner loop. Epilogue writes the identical packed-bf16
// h bits into LDS sHs (row stride 72). After one barrier the original
// 256-thr gemm body (xf32=0) consumes sHs -> layer-2 Ts/Rs.
__global__ __launch_bounds__(256) void gather_gemm(
    const uint2* __restrict__ Ts2, const uint2* __restrict__ Rs2,
    const int* __restrict__ es, const int* __restrict__ nstart,
    const int* __restrict__ ndeg, const float* __restrict__ dinv,
    const ushort16* __restrict__ wt4, const float* __restrict__ bias,
    ushort16* __restrict__ To, ushort16* __restrict__ Ro, int n) {
    __shared__ unsigned short sHs[64 * 72];   // 9216 B
    int t = threadIdx.x;
    int w = t >> 6, lane = t & 63;
    int q = lane >> 4, d4 = lane & 15;
    int node0 = blockIdx.x * 64;

    for (int rd = 0; rd < 16; ++rd) {
        int cl = w * 16 + rd;
        int c = node0 + cl;
        if (c < n) {
            int deg = ndeg[c];
            int s0 = nstart[c];
            float a0 = 0.f, a1 = 0.f, a2 = 0.f, a3 = 0.f;
            for (int base = 0; base < deg; base += 64) {
                int m = min(deg - base, 64);
                int sid = (lane < m) ? es[s0 + base + lane] : 0;
                for (int j = 0; j < m; j += 16) {
                    int e0 = j + q, e1 = j + 4 + q, e2 = j + 8 + q, e3 = j + 12 + q;
                    int r0 = __shfl(sid, e0);
                    int r1 = __shfl(sid, e1);
                    int r2 = __shfl(sid, e2);
                    int r3 = __shfl(sid, e3);
                    uint2 z = make_uint2(0u, 0u);
                    uint2 v0 = (e0 < m) ? Ts2[(size_t)r0 * 16 + d4] : z;
                    uint2 v1 = (e1 < m) ? Ts2[(size_t)r1 * 16 + d4] : z;
                    uint2 v2 = (e2 < m) ? Ts2[(size_t)r2 * 16 + d4] : z;
                    uint2 v3 = (e3 < m) ? Ts2[(size_t)r3 * 16 + d4] : z;
                    a0 += bflo(v0.x) + bflo(v1.x) + bflo(v2.x) + bflo(v3.x);
                    a1 += bfhi(v0.x) + bfhi(v1.x) + bfhi(v2.x) + bfhi(v3.x);
                    a2 += bflo(v0.y) + bflo(v1.y) + bflo(v2.y) + bflo(v3.y);
                    a3 += bfhi(v0.y) + bfhi(v1.y) + bfhi(v2.y) + bfhi(v3.y);
                }
            }
            a0 += __shfl_xor(a0, 16); a0 += __shfl_xor(a0, 32);
            a1 += __shfl_xor(a1, 16); a1 += __shfl_xor(a1, 32);
            a2 += __shfl_xor(a2, 16); a2 += __shfl_xor(a2, 32);
            a3 += __shfl_xor(a3, 16); a3 += __shfl_xor(a3, 32);
            if (lane < 16) {
                float dc = dinv[c];
                uint2 ur = Rs2[(size_t)c * 16 + d4];
                float h0 = fmaxf(fmaf(dc, a0, bflo(ur.x)), 0.0f);
                float h1 = fmaxf(fmaf(dc, a1, bfhi(ur.x)), 0.0f);
                float h2 = fmaxf(fmaf(dc, a2, bflo(ur.y)), 0.0f);
                float h3 = fmaxf(fmaf(dc, a3, bfhi(ur.y)), 0.0f);
                *(uint2*)&sHs[cl * 72 + d4 * 4] =
                    make_uint2(pack_bf16(h0, h1), pack_bf16(h2, h3));
            }
        } else {
            if (lane < 16)
                *(uint2*)&sHs[cl * 72 + d4 * 4] = make_uint2(0u, 0u);
        }
    }
    __syncthreads();

    // ---- layer-2 gemm (original 256-thr body, reads sHs) ----
    int colx = lane & 15;
    int dim = w * 16 + colx;

    short8 bih[2], bil[2], brh[2], brl[2];
#pragma unroll
    for (int kh = 0; kh < 2; ++kh) {
        size_t o = (size_t)dim * 64 + kh * 32 + q * 8;
        bih[kh] = *(const short8*)&wt4[0 * 4096 + o];
        bil[kh] = *(const short8*)&wt4[1 * 4096 + o];
        brh[kh] = *(const short8*)&wt4[2 * 4096 + o];
        brl[kh] = *(const short8*)&wt4[3 * 4096 + o];
    }
    float4 bias4 = *(const float4*)&bias[w * 16 + q * 4];

    unsigned short* ToU = (unsigned short*)To;
    unsigned short* RoU = (unsigned short*)Ro;

#pragma unroll
    for (int mt = 0; mt < 4; ++mt) {
        int rbase = mt * 16 + colx;
        short8 a0 = *(const short8*)&sHs[rbase * 72 + q * 8];
        short8 a1 = *(const short8*)&sHs[rbase * 72 + 32 + q * 8];
        f32x4 accT = {0.f, 0.f, 0.f, 0.f};
        f32x4 accR = {0.f, 0.f, 0.f, 0.f};
        accT = __builtin_amdgcn_mfma_f32_16x16x32_bf16(bih[0], a0, accT, 0, 0, 0);
        accT = __builtin_amdgcn_mfma_f32_16x16x32_bf16(bih[1], a1, accT, 0, 0, 0);
        accT = __builtin_amdgcn_mfma_f32_16x16x32_bf16(bil[0], a0, accT, 0, 0, 0);
        accT = __builtin_amdgcn_mfma_f32_16x16x32_bf16(bil[1], a1, accT, 0, 0, 0);
        accR = __builtin_amdgcn_mfma_f32_16x16x32_bf16(brh[0], a0, accR, 0, 0, 0);
        accR = __builtin_amdgcn_mfma_f32_16x16x32_bf16(brh[1], a1, accR, 0, 0, 0);
        accR = __builtin_amdgcn_mfma_f32_16x16x32_bf16(brl[0], a0, accR, 0, 0, 0);
        accR = __builtin_amdgcn_mfma_f32_16x16x32_bf16(brl[1], a1, accR, 0, 0, 0);

        int node = node0 + mt * 16 + colx;
        if (node < n) {
            float dv = dinv[node];
            uint2 pT, pR;
            pT.x = pack_bf16(accT[0] * dv, accT[1] * dv);
            pT.y = pack_bf16(accT[2] * dv, accT[3] * dv);
            pR.x = pack_bf16(accR[0] + bias4.x, accR[1] + bias4.y);
            pR.y = pack_bf16(accR[2] + bias4.z, accR[3] + bias4.w);
            size_t o = (size_t)node * 64 + w * 16 + q * 4;
            *(uint2*)&ToU[o] = pT;
            *(uint2*)&RoU[o] = pR;
        }
    }
}

// ---------------- fused gather-propagate + relu (layer 2, unchanged) ----------------
__global__ __launch_bounds__(256) void gather_fused(
    const uint2* __restrict__ Ts2, const uint2* __restrict__ Rs2,
    const int* __restrict__ es, const int* __restrict__ nstart,
    const int* __restrict__ ndeg, const float* __restrict__ dinv,
    uint2* __restrict__ Hb2, int n) {
    int c = blockIdx.x * 4 + (threadIdx.x >> 6);
    if (c >= n) return;
    int lane = threadIdx.x & 63;
    int q = lane >> 4;    // edge slot 0..3
    int d4 = lane & 15;   // dim quad
    int deg = ndeg[c];
    int s0 = nstart[c];
    float a0 = 0.f, a1 = 0.f, a2 = 0.f, a3 = 0.f;
    for (int base = 0; base < deg; base += 64) {
        int m = min(deg - base, 64);
        int sid = (lane < m) ? es[s0 + base + lane] : 0;
        for (int j = 0; j < m; j += 16) {
            int e0 = j + q, e1 = j + 4 + q, e2 = j + 8 + q, e3 = j + 12 + q;
            int r0 = __shfl(sid, e0);
            int r1 = __shfl(sid, e1);
            int r2 = __shfl(sid, e2);
            int r3 = __shfl(sid, e3);
            uint2 z = make_uint2(0u, 0u);
            uint2 v0 = (e0 < m) ? Ts2[(size_t)r0 * 16 + d4] : z;
            uint2 v1 = (e1 < m) ? Ts2[(size_t)r1 * 16 + d4] : z;
            uint2 v2 = (e2 < m) ? Ts2[(size_t)r2 * 16 + d4] : z;
            uint2 v3 = (e3 < m) ? Ts2[(size_t)r3 * 16 + d4] : z;
            a0 += bflo(v0.x) + bflo(v1.x) + bflo(v2.x) + bflo(v3.x);
            a1 += bfhi(v0.x) + bfhi(v1.x) + bfhi(v2.x) + bfhi(v3.x);
            a2 += bflo(v0.y) + bflo(v1.y) + bflo(v2.y) + bflo(v3.y);
            a3 += bfhi(v0.y) + bfhi(v1.y) + bfhi(v2.y) + bfhi(v3.y);
        }
    }
    a0 += __shfl_xor(a0, 16); a0 += __shfl_xor(a0, 32);
    a1 += __shfl_xor(a1, 16); a1 += __shfl_xor(a1, 32);
    a2 += __shfl_xor(a2, 16); a2 += __shfl_xor(a2, 32);
    a3 += __shfl_xor(a3, 16); a3 += __shfl_xor(a3, 32);
    if (lane < 16) {
        float dc = dinv[c];
        uint2 ur = Rs2[(size_t)c * 16 + d4];
        float h0 = fmaxf(fmaf(dc, a0, bflo(ur.x)), 0.0f);
        float h1 = fmaxf(fmaf(dc, a1, bfhi(ur.x)), 0.0f);
        float h2 = fmaxf(fmaf(dc, a2, bflo(ur.y)), 0.0f);
        float h3 = fmaxf(fmaf(dc, a3, bfhi(ur.y)), 0.0f);
        Hb2[(size_t)c * 16 + d4] = make_uint2(pack_bf16(h0, h1), pack_bf16(h2, h3));
    }
}

// ---------------- mean-pool over sorted batch: 64 nodes/block (R25) ----------------
__global__ __launch_bounds__(256) void pool_kernel(
    const uint32* __restrict__ Hb, const int* __restrict__ batch,
    float* __restrict__ pooled, float* __restrict__ cnt, int n) {
    __shared__ float sAcc[64 * 64];
    __shared__ float sCnt[64];
    int tid = threadIdx.x;
    for (int i = tid; i < 4096; i += 256) sAcc[i] = 0.0f;
    if (tid < 64) sCnt[tid] = 0.0f;
    __syncthreads();

    int w = tid >> 6, lane = tid & 63;
    int half = lane >> 5, d2 = lane & 31;
    int s = blockIdx.x * 64 + w * 16;
    int e = min(s + 16, n);
    float a0 = 0.0f, a1 = 0.0f, c = 0.0f;
    int gcur = -1;
    for (int i = s + half; i < e; i += 2) {
        int g = batch[i];
        if (g != gcur) {
            if (gcur >= 0) {
                atomicAdd(&sAcc[gcur * 64 + 2 * d2], a0);
                atomicAdd(&sAcc[gcur * 64 + 2 * d2 + 1], a1);
                if (d2 == 0) atomicAdd(&sCnt[gcur], c);
            }
            gcur = g; a0 = 0.0f; a1 = 0.0f; c = 0.0f;
        }
        uint32 u = Hb[(size_t)i * 32 + d2];
        a0 += bflo(u);
        a1 += bfhi(u);
        c += 1.0f;
    }
    if (gcur >= 0) {
        atomicAdd(&sAcc[gcur * 64 + 2 * d2], a0);
        atomicAdd(&sAcc[gcur * 64 + 2 * d2 + 1], a1);
        if (d2 == 0) atomicAdd(&sCnt[gcur], c);
    }
    __syncthreads();
    for (int i = tid; i < 4096; i += 256) {
        float v = sAcc[i];
        if (v != 0.0f) atomicAdd(&pooled[i], v);
    }
    if (tid < 64) {
        float v = sCnt[tid];
        if (v != 0.0f) atomicAdd(&cnt[tid], v);
    }
}

// ---------------- out[g,o] = (pooled[g,:]/max(cnt,1)) @ fcw + fcb ----------------
__global__ void final_fc(const float* __restrict__ pooled, const float* __restrict__ cnt,
                         const float* __restrict__ fcw, const float* __restrict__ fcb,
                         float* __restrict__ out) {
    int idx = blockIdx.x * 256 + threadIdx.x;
    if (idx >= 64 * 32) return;
    int g = idx >> 5, o = idx & 31;
    float c = fmaxf(cnt[g], 1.0f);
    float acc = 0.0f;
#pragma unroll
    for (int k = 0; k < 64; ++k) acc = fmaf(pooled[g * 64 + k], fcw[k * 32 + o], acc);
    out[idx] = acc / c + fcb[o];
}

extern "C" void kernel_launch(void* const* d_in, const int* in_sizes, int n_in,
                              void* d_out, int out_size, void* d_ws, size_t ws_size,
                              hipStream_t stream) {
    const float* x       = (const float*)d_in[0];
    const int*   eidx    = (const int*)d_in[1];
    const int*   batch   = (const int*)d_in[2];
    const float* w1_init = (const float*)d_in[3];
    const float* w1_root = (const float*)d_in[4];
    const float* b1      = (const float*)d_in[5];
    const float* w2_init = (const float*)d_in[6];
    const float* w2_root = (const float*)d_in[7];
    const float* b2      = (const float*)d_in[8];
    const float* fc_w    = (const float*)d_in[9];
    const float* fc_b    = (const float*)d_in[10];
    float* out = (float*)d_out;

    const int N = in_sizes[0] / 64;
    const int E = in_sizes[1] / 2;
    const int* row = eidx;
    const int* col = eidx + E;

    const int B = (N + NB - 1) / NB;  // 391 buckets

    // workspace (4-byte units):
    // bpack(B*CAP) | es(B*CAP) | [zeroed: bcnt(MAXB) | pooled(4096) | cnt(64)]
    // | nstart(N) | ndeg(N) | dinv(N) | wt(16384) | Ts1(N*32) | Rs1(N*32)
    // | T2(N*32) | R2(N*32)
    // After gather_gemm, Ts1/Rs1 are dead; gather2 writes H into Ts1 region.
    uint32* bpack = (uint32*)d_ws;
    int*   es     = (int*)(bpack + (size_t)B * CAP);
    int*   bcnt   = es + (size_t)B * CAP;
    float* pooled = (float*)(bcnt + MAXB);
    float* cnt    = pooled + 64 * 64;
    int*   nstart = (int*)(cnt + 64);
    int*   ndeg   = nstart + N;
    float* dinv   = (float*)(ndeg + N);
    uint32* wtU   = (uint32*)(dinv + N);            // 16384 uints (64 KB)
    uint32* Ts1   = wtU + 16384;                    // N*32
    uint32* Rs1   = Ts1 + (size_t)N * 32;           // N*32
    uint32* T2    = Rs1 + (size_t)N * 32;           // N*32
    uint32* R2    = T2 + (size_t)N * 32;            // N*32
    ushort16* wt  = (ushort16*)wtU;

    hipMemsetAsync(bcnt, 0, (size_t)(MAXB + 64 * 64 + 64) * sizeof(int), stream);

    // bucket + fused weight prep
    const int EB = (E + P1_CHUNK - 1) / P1_CHUNK;
    bucket_kernel<<<128 + EB, 256, 0, stream>>>(row, col, bpack, bcnt, E,
                                                w1_init, w1_root, w2_init, w2_root, wt);

    // CSR build + fused layer-1 gemm
    csr_gemm<<<B, 1024, 0, stream>>>(bpack, bcnt, es, nstart, ndeg, dinv,
                                     x, wt, b1, (ushort16*)Ts1, (ushort16*)Rs1, N);

    // gather1 + fused layer-2 gemm
    gather_gemm<<<(N + 63) / 64, 256, 0, stream>>>(
        (const uint2*)Ts1, (const uint2*)Rs1, es, nstart, ndeg, dinv,
        wt + (size_t)4 * 4096, b2, (ushort16*)T2, (ushort16*)R2, N);

    // gather2 -> H (reuses dead Ts1 region)
    gather_fused<<<(N + 3) / 4, 256, 0, stream>>>(
        (const uint2*)T2, (const uint2*)R2, es, nstart, ndeg, dinv,
        (uint2*)Ts1, N);

    // pool + FC
    pool_kernel<<<(N + 63) / 64, 256, 0, stream>>>(Ts1, batch, pooled, cnt, N);
    final_fc<<<(64 * 32 + 255) / 256, 256, 0, stream>>>(pooled, cnt, fc_w, fc_b, out);
}

// Round 9
// 271.604 us; speedup vs baseline: 2.5801x; 1.0382x over previous
//
#include <hip/hip_runtime.h>
#include <hip/hip_bf16.h>

// ARMANet: 2x ARMAConv(K=1,T=1) + global mean pool + FC
// N=100000 nodes, E=1600000 edges, IN=HID=64, OUT=32, G=64 graphs.
// R28 = R27 resubmitted verbatim (R8 bench was a container-acquisition
// failure; kernel never measured).
//  - Layer-2 H is consumed ONLY by pool -> gather2 never writes it.
//    gather_pool: 64 dests/block (4 waves x 16 serial rounds, inner pull
//    loop unchanged), h quantized to bf16 (identical bits to old stored H)
//    then accumulated into per-wave register partials per graph (batch
//    sorted -> ~1-2 flushes/wave into 16KB LDS sAcc), block-end flush of
//    nonzero entries to global pooled atomics (~128/block x 1563 blocks).
//    Kills pool dispatch, one boundary, H write+read (25.3 MB).
//  - bucket(+wprep), csr_gemm (csr + layer-1 MFMA), gather_gemm (gather1 +
//    layer-2 MFMA), final_fc unchanged from R26 (282.0us best).
//  Dispatches: bucket, csr_gemm, gather_gemm, gather_pool, fc (5 + memset).

#define NB 256
#define CAP 5120
#define MAXB 400
#define P1_CHUNK 2048

typedef unsigned int uint32;
typedef unsigned short ushort16;
typedef __attribute__((ext_vector_type(8))) short short8;   // 8 bf16 (4 VGPRs)
typedef __attribute__((ext_vector_type(4))) float f32x4;    // MFMA C/D

__device__ inline uint32 bf16rn(float f) {
    uint32 u = __float_as_uint(f);
    uint32 r = ((u >> 16) & 1u) + 0x7FFFu;
    return (u + r) >> 16;
}
__device__ inline uint32 pack_bf16(float a, float b) {
    return bf16rn(a) | (bf16rn(b) << 16);
}
__device__ inline float bflo(uint32 u) { return __uint_as_float(u << 16); }
__device__ inline float bfhi(uint32 u) { return __uint_as_float(u & 0xFFFF0000u); }

// ---------------- stage 1: bucket edges by destination (+ fused weight prep) ----------------
__global__ __launch_bounds__(256) void bucket_kernel(
    const int* __restrict__ row, const int* __restrict__ col,
    uint32* __restrict__ bpack, int* __restrict__ bcnt, int E,
    const float* __restrict__ W1i, const float* __restrict__ W1r,
    const float* __restrict__ W2i, const float* __restrict__ W2r,
    ushort16* __restrict__ wt) {
    __shared__ int hist[MAXB];
    __shared__ int ofs[MAXB];
    __shared__ int cur[MAXB];
    __shared__ int gbase[MAXB];
    __shared__ int s[256];
    __shared__ uint32 stage[P1_CHUNK];
    __shared__ unsigned short stage_bk[P1_CHUNK];

    int t = threadIdx.x;

    if (blockIdx.x < 128) {
        // ---- wprep role ----
        int idx = blockIdx.x * 256 + t;     // 8*4096 items over 128 blocks
        int m = idx >> 12;
        int r = idx & 4095;
        int d = r >> 6, k = r & 63;
        const float* W = (m < 2) ? W1i : (m < 4) ? W1r : (m < 6) ? W2i : W2r;
        float v = W[k * 64 + d];
        uint32 hi = bf16rn(v);
        uint32 outv;
        if (m & 1) {
            float hf = __uint_as_float(hi << 16);
            outv = bf16rn(v - hf);
        } else {
            outv = hi;
        }
        wt[(size_t)m * 4096 + d * 64 + k] = (unsigned short)outv;
        return;
    }

    for (int i = t; i < MAXB; i += 256) hist[i] = 0;
    __syncthreads();

    int e0 = (blockIdx.x - 128) * P1_CHUNK;
    int cntE = min(E - e0, P1_CHUNK);

    for (int i = t; i < cntE; i += 256) {
        int c = col[e0 + i];
        atomicAdd(&hist[c >> 8], 1);
    }
    __syncthreads();

    int i2 = 2 * t;
    int a = (i2 < MAXB) ? hist[i2] : 0;
    int b = (i2 + 1 < MAXB) ? hist[i2 + 1] : 0;
    s[t] = a + b;
    __syncthreads();
    for (int off = 1; off < 256; off <<= 1) {
        int x = (t >= off) ? s[t - off] : 0;
        __syncthreads();
        s[t] += x;
        __syncthreads();
    }
    int excl = (t > 0) ? s[t - 1] : 0;
    if (i2 < MAXB) ofs[i2] = excl;
    if (i2 + 1 < MAXB) ofs[i2 + 1] = excl + a;
    __syncthreads();

    for (int i = t; i < MAXB; i += 256) {
        cur[i] = ofs[i];
        gbase[i] = hist[i] ? atomicAdd(&bcnt[i], hist[i]) : 0;
    }
    __syncthreads();

    for (int i = t; i < cntE; i += 256) {
        int c = col[e0 + i];
        int r = row[e0 + i];
        int bk = c >> 8;
        int k = atomicAdd(&cur[bk], 1);
        stage[k] = ((uint32)(c & 255) << 24) | (uint32)r;
        stage_bk[k] = (unsigned short)bk;
    }
    __syncthreads();

    for (int i = t; i < cntE; i += 256) {
        uint32 pk = stage[i];
        int bk = stage_bk[i];
        int gd = gbase[bk] + (i - ofs[bk]);
        if (gd < CAP) bpack[(size_t)bk * CAP + gd] = pk;
    }
}

// ---------------- stage 2: per-bucket counting sort -> CSR + dinv, FUSED layer-1 gemm ----------------
__global__ __launch_bounds__(1024) void csr_gemm(
    const uint32* __restrict__ bpack, const int* __restrict__ bcnt,
    int* __restrict__ es, int* __restrict__ nstart, int* __restrict__ ndeg,
    float* __restrict__ dinv,
    const float* __restrict__ X, const ushort16* __restrict__ wt4,
    const float* __restrict__ bias,
    ushort16* __restrict__ Ts, ushort16* __restrict__ Rs, int n) {
    __shared__ int h[NB];
    __shared__ alignas(16) unsigned char uni[36864];   // max(csr 22.5KB, sXs 36.9KB)
    uint32* sbp = (uint32*)uni;                         // [CAP]   20480 B
    int* s      = (int*)(uni + 20480);                  // [NB]
    int* cur    = (int*)(uni + 21504);                  // [NB]
    unsigned short* sXs = (unsigned short*)uni;         // [4][64*72] phase B

    int b = blockIdx.x, t = threadIdx.x;
    if (t < NB) h[t] = 0;
    __syncthreads();
    int cnt = min(bcnt[b], CAP);
    size_t base = (size_t)b * CAP;
    for (int i = t; i < cnt; i += 1024) {
        uint32 pk = bpack[base + i];
        sbp[i] = pk;
        atomicAdd(&h[pk >> 24], 1);
    }
    __syncthreads();
    if (t < NB) s[t] = h[t];
    __syncthreads();
    for (int off = 1; off < NB; off <<= 1) {
        int x = 0;
        if (t < NB && t >= off) x = s[t - off];
        __syncthreads();
        if (t < NB) s[t] += x;
        __syncthreads();
    }
    if (t < NB) {
        int myofs = s[t] - h[t];
        cur[t] = myofs;
        int node = b * NB + t;
        if (node < n) {
            nstart[node] = (int)base + myofs;
            ndeg[node] = h[t];
            dinv[node] = h[t] ? rsqrtf((float)h[t]) : 0.0f;
        }
    }
    __syncthreads();
    for (int i = t; i < cnt; i += 1024) {
        uint32 pk = sbp[i];
        int cl = (int)(pk >> 24);
        int p = atomicAdd(&cur[cl], 1);
        es[base + p] = (int)(pk & 0xFFFFFFu);
    }
    __syncthreads();   // sbp fully consumed; union switches to sXs

    // ---- Phase B: stage X (4 tiles x [64 rows x 72 bf16]) ----
    for (int i = t; i < 4096; i += 1024) {
        int tile = i >> 10, j = i & 1023;
        int r = j >> 4, c4 = (j & 15) * 4;
        int node = b * NB + tile * 64 + r;
        float4 v = make_float4(0.f, 0.f, 0.f, 0.f);
        if (node < n) v = *(const float4*)&X[(size_t)node * 64 + c4];
        *(uint32*)&sXs[tile * 4608 + r * 72 + c4] = pack_bf16(v.x, v.y);
        *(uint32*)&sXs[tile * 4608 + r * 72 + c4 + 2] = pack_bf16(v.z, v.w);
    }
    __syncthreads();

    // ---- MFMA: wave wv -> tile wv>>2, dim-quadrant wv&3 ----
    int wv = t >> 6, lane = t & 63;
    int tile = wv >> 2, wq = wv & 3;
    int q = lane >> 4, colx = lane & 15;
    int dim = wq * 16 + colx;

    short8 bih[2], bil[2], brh[2], brl[2];
#pragma unroll
    for (int kh = 0; kh < 2; ++kh) {
        size_t o = (size_t)dim * 64 + kh * 32 + q * 8;
        bih[kh] = *(const short8*)&wt4[0 * 4096 + o];
        bil[kh] = *(const short8*)&wt4[1 * 4096 + o];
        brh[kh] = *(const short8*)&wt4[2 * 4096 + o];
        brl[kh] = *(const short8*)&wt4[3 * 4096 + o];
    }
    float4 bias4 = *(const float4*)&bias[wq * 16 + q * 4];

    unsigned short* TsU = (unsigned short*)Ts;
    unsigned short* RsU = (unsigned short*)Rs;

#pragma unroll
    for (int mt = 0; mt < 4; ++mt) {
        int rbase = mt * 16 + colx;
        short8 a0 = *(const short8*)&sXs[tile * 4608 + rbase * 72 + q * 8];
        short8 a1 = *(const short8*)&sXs[tile * 4608 + rbase * 72 + 32 + q * 8];
        f32x4 accT = {0.f, 0.f, 0.f, 0.f};
        f32x4 accR = {0.f, 0.f, 0.f, 0.f};
        accT = __builtin_amdgcn_mfma_f32_16x16x32_bf16(bih[0], a0, accT, 0, 0, 0);
        accT = __builtin_amdgcn_mfma_f32_16x16x32_bf16(bih[1], a1, accT, 0, 0, 0);
        accT = __builtin_amdgcn_mfma_f32_16x16x32_bf16(bil[0], a0, accT, 0, 0, 0);
        accT = __builtin_amdgcn_mfma_f32_16x16x32_bf16(bil[1], a1, accT, 0, 0, 0);
        accR = __builtin_amdgcn_mfma_f32_16x16x32_bf16(brh[0], a0, accR, 0, 0, 0);
        accR = __builtin_amdgcn_mfma_f32_16x16x32_bf16(brh[1], a1, accR, 0, 0, 0);
        accR = __builtin_amdgcn_mfma_f32_16x16x32_bf16(brl[0], a0, accR, 0, 0, 0);
        accR = __builtin_amdgcn_mfma_f32_16x16x32_bf16(brl[1], a1, accR, 0, 0, 0);

        int li = tile * 64 + mt * 16 + colx;
        int node = b * NB + li;
        if (node < n) {
            int dg = h[li];
            float dv = dg ? rsqrtf((float)dg) : 0.0f;   // identical to csr dinv
            uint2 pT, pR;
            pT.x = pack_bf16(accT[0] * dv, accT[1] * dv);
            pT.y = pack_bf16(accT[2] * dv, accT[3] * dv);
            pR.x = pack_bf16(accR[0] + bias4.x, accR[1] + bias4.y);
            pR.y = pack_bf16(accR[2] + bias4.z, accR[3] + bias4.w);
            size_t o = (size_t)node * 64 + wq * 16 + q * 4;
            *(uint2*)&TsU[o] = pT;
            *(uint2*)&RsU[o] = pR;
        }
    }
}

// ---------------- gather1 + layer-2 gemm fused ----------------
__global__ __launch_bounds__(256) void gather_gemm(
    const uint2* __restrict__ Ts2, const uint2* __restrict__ Rs2,
    const int* __restrict__ es, const int* __restrict__ nstart,
    const int* __restrict__ ndeg, const float* __restrict__ dinv,
    const ushort16* __restrict__ wt4, const float* __restrict__ bias,
    ushort16* __restrict__ To, ushort16* __restrict__ Ro, int n) {
    __shared__ unsigned short sHs[64 * 72];   // 9216 B
    int t = threadIdx.x;
    int w = t >> 6, lane = t & 63;
    int q = lane >> 4, d4 = lane & 15;
    int node0 = blockIdx.x * 64;

    for (int rd = 0; rd < 16; ++rd) {
        int cl = w * 16 + rd;
        int c = node0 + cl;
        if (c < n) {
            int deg = ndeg[c];
            int s0 = nstart[c];
            float a0 = 0.f, a1 = 0.f, a2 = 0.f, a3 = 0.f;
            for (int base = 0; base < deg; base += 64) {
                int m = min(deg - base, 64);
                int sid = (lane < m) ? es[s0 + base + lane] : 0;
                for (int j = 0; j < m; j += 16) {
                    int e0 = j + q, e1 = j + 4 + q, e2 = j + 8 + q, e3 = j + 12 + q;
                    int r0 = __shfl(sid, e0);
                    int r1 = __shfl(sid, e1);
                    int r2 = __shfl(sid, e2);
                    int r3 = __shfl(sid, e3);
                    uint2 z = make_uint2(0u, 0u);
                    uint2 v0 = (e0 < m) ? Ts2[(size_t)r0 * 16 + d4] : z;
                    uint2 v1 = (e1 < m) ? Ts2[(size_t)r1 * 16 + d4] : z;
                    uint2 v2 = (e2 < m) ? Ts2[(size_t)r2 * 16 + d4] : z;
                    uint2 v3 = (e3 < m) ? Ts2[(size_t)r3 * 16 + d4] : z;
                    a0 += bflo(v0.x) + bflo(v1.x) + bflo(v2.x) + bflo(v3.x);
                    a1 += bfhi(v0.x) + bfhi(v1.x) + bfhi(v2.x) + bfhi(v3.x);
                    a2 += bflo(v0.y) + bflo(v1.y) + bflo(v2.y) + bflo(v3.y);
                    a3 += bfhi(v0.y) + bfhi(v1.y) + bfhi(v2.y) + bfhi(v3.y);
                }
            }
            a0 += __shfl_xor(a0, 16); a0 += __shfl_xor(a0, 32);
            a1 += __shfl_xor(a1, 16); a1 += __shfl_xor(a1, 32);
            a2 += __shfl_xor(a2, 16); a2 += __shfl_xor(a2, 32);
            a3 += __shfl_xor(a3, 16); a3 += __shfl_xor(a3, 32);
            if (lane < 16) {
                float dc = dinv[c];
                uint2 ur = Rs2[(size_t)c * 16 + d4];
                float h0 = fmaxf(fmaf(dc, a0, bflo(ur.x)), 0.0f);
                float h1 = fmaxf(fmaf(dc, a1, bfhi(ur.x)), 0.0f);
                float h2 = fmaxf(fmaf(dc, a2, bflo(ur.y)), 0.0f);
                float h3 = fmaxf(fmaf(dc, a3, bfhi(ur.y)), 0.0f);
                *(uint2*)&sHs[cl * 72 + d4 * 4] =
                    make_uint2(pack_bf16(h0, h1), pack_bf16(h2, h3));
            }
        } else {
            if (lane < 16)
                *(uint2*)&sHs[cl * 72 + d4 * 4] = make_uint2(0u, 0u);
        }
    }
    __syncthreads();

    // ---- layer-2 gemm (original 256-thr body, reads sHs) ----
    int colx = lane & 15;
    int dim = w * 16 + colx;

    short8 bih[2], bil[2], brh[2], brl[2];
#pragma unroll
    for (int kh = 0; kh < 2; ++kh) {
        size_t o = (size_t)dim * 64 + kh * 32 + q * 8;
        bih[kh] = *(const short8*)&wt4[0 * 4096 + o];
        bil[kh] = *(const short8*)&wt4[1 * 4096 + o];
        brh[kh] = *(const short8*)&wt4[2 * 4096 + o];
        brl[kh] = *(const short8*)&wt4[3 * 4096 + o];
    }
    float4 bias4 = *(const float4*)&bias[w * 16 + q * 4];

    unsigned short* ToU = (unsigned short*)To;
    unsigned short* RoU = (unsigned short*)Ro;

#pragma unroll
    for (int mt = 0; mt < 4; ++mt) {
        int rbase = mt * 16 + colx;
        short8 a0 = *(const short8*)&sHs[rbase * 72 + q * 8];
        short8 a1 = *(const short8*)&sHs[rbase * 72 + 32 + q * 8];
        f32x4 accT = {0.f, 0.f, 0.f, 0.f};
        f32x4 accR = {0.f, 0.f, 0.f, 0.f};
        accT = __builtin_amdgcn_mfma_f32_16x16x32_bf16(bih[0], a0, accT, 0, 0, 0);
        accT = __builtin_amdgcn_mfma_f32_16x16x32_bf16(bih[1], a1, accT, 0, 0, 0);
        accT = __builtin_amdgcn_mfma_f32_16x16x32_bf16(bil[0], a0, accT, 0, 0, 0);
        accT = __builtin_amdgcn_mfma_f32_16x16x32_bf16(bil[1], a1, accT, 0, 0, 0);
        accR = __builtin_amdgcn_mfma_f32_16x16x32_bf16(brh[0], a0, accR, 0, 0, 0);
        accR = __builtin_amdgcn_mfma_f32_16x16x32_bf16(brh[1], a1, accR, 0, 0, 0);
        accR = __builtin_amdgcn_mfma_f32_16x16x32_bf16(brl[0], a0, accR, 0, 0, 0);
        accR = __builtin_amdgcn_mfma_f32_16x16x32_bf16(brl[1], a1, accR, 0, 0, 0);

        int node = node0 + mt * 16 + colx;
        if (node < n) {
            float dv = dinv[node];
            uint2 pT, pR;
            pT.x = pack_bf16(accT[0] * dv, accT[1] * dv);
            pT.y = pack_bf16(accT[2] * dv, accT[3] * dv);
            pR.x = pack_bf16(accR[0] + bias4.x, accR[1] + bias4.y);
            pR.y = pack_bf16(accR[2] + bias4.z, accR[3] + bias4.w);
            size_t o = (size_t)node * 64 + w * 16 + q * 4;
            *(uint2*)&ToU[o] = pT;
            *(uint2*)&RoU[o] = pR;
        }
    }
}

// ---------------- gather2 + mean-pool fused (H never materialized) ----------------
// Block = 64 dests (4 waves x 16 serial rounds, inner pull loop unchanged).
// h is bf16-quantized (identical bits to the H that used to be stored), then
// accumulated per-graph in wave registers (batch sorted -> ~1-2 flushes into
// LDS sAcc), block-end flush of nonzero entries to global pooled atomics.
__global__ __launch_bounds__(256) void gather_pool(
    const uint2* __restrict__ Ts2, const uint2* __restrict__ Rs2,
    const int* __restrict__ es, const int* __restrict__ nstart,
    const int* __restrict__ ndeg, const float* __restrict__ dinv,
    const int* __restrict__ batch,
    float* __restrict__ pooled, float* __restrict__ cnt, int n) {
    __shared__ float sAcc[64 * 64];   // 16 KB
    __shared__ float sCnt[64];
    int t = threadIdx.x;
    for (int i = t; i < 4096; i += 256) sAcc[i] = 0.0f;
    if (t < 64) sCnt[t] = 0.0f;
    __syncthreads();

    int w = t >> 6, lane = t & 63;
    int q = lane >> 4, d4 = lane & 15;
    int node0 = blockIdx.x * 64;

    int gcur = -1;
    float p0 = 0.f, p1 = 0.f, p2 = 0.f, p3 = 0.f, pc = 0.f;

    for (int rd = 0; rd < 16; ++rd) {
        int c = node0 + w * 16 + rd;
        if (c < n) {
            int g = batch[c];
            if (g != gcur) {                     // wave-uniform branch
                if (gcur >= 0 && lane < 16) {
                    atomicAdd(&sAcc[gcur * 64 + d4 * 4 + 0], p0);
                    atomicAdd(&sAcc[gcur * 64 + d4 * 4 + 1], p1);
                    atomicAdd(&sAcc[gcur * 64 + d4 * 4 + 2], p2);
                    atomicAdd(&sAcc[gcur * 64 + d4 * 4 + 3], p3);
                    if (d4 == 0) atomicAdd(&sCnt[gcur], pc);
                }
                gcur = g;
                p0 = p1 = p2 = p3 = 0.f; pc = 0.f;
            }
            int deg = ndeg[c];
            int s0 = nstart[c];
            float a0 = 0.f, a1 = 0.f, a2 = 0.f, a3 = 0.f;
            for (int base = 0; base < deg; base += 64) {
                int m = min(deg - base, 64);
                int sid = (lane < m) ? es[s0 + base + lane] : 0;
                for (int j = 0; j < m; j += 16) {
                    int e0 = j + q, e1 = j + 4 + q, e2 = j + 8 + q, e3 = j + 12 + q;
                    int r0 = __shfl(sid, e0);
                    int r1 = __shfl(sid, e1);
                    int r2 = __shfl(sid, e2);
                    int r3 = __shfl(sid, e3);
                    uint2 z = make_uint2(0u, 0u);
                    uint2 v0 = (e0 < m) ? Ts2[(size_t)r0 * 16 + d4] : z;
                    uint2 v1 = (e1 < m) ? Ts2[(size_t)r1 * 16 + d4] : z;
                    uint2 v2 = (e2 < m) ? Ts2[(size_t)r2 * 16 + d4] : z;
                    uint2 v3 = (e3 < m) ? Ts2[(size_t)r3 * 16 + d4] : z;
                    a0 += bflo(v0.x) + bflo(v1.x) + bflo(v2.x) + bflo(v3.x);
                    a1 += bfhi(v0.x) + bfhi(v1.x) + bfhi(v2.x) + bfhi(v3.x);
                    a2 += bflo(v0.y) + bflo(v1.y) + bflo(v2.y) + bflo(v3.y);
                    a3 += bfhi(v0.y) + bfhi(v1.y) + bfhi(v2.y) + bfhi(v3.y);
                }
            }
            a0 += __shfl_xor(a0, 16); a0 += __shfl_xor(a0, 32);
            a1 += __shfl_xor(a1, 16); a1 += __shfl_xor(a1, 32);
            a2 += __shfl_xor(a2, 16); a2 += __shfl_xor(a2, 32);
            a3 += __shfl_xor(a3, 16); a3 += __shfl_xor(a3, 32);
            if (lane < 16) {
                float dc = dinv[c];
                uint2 ur = Rs2[(size_t)c * 16 + d4];
                float h0 = fmaxf(fmaf(dc, a0, bflo(ur.x)), 0.0f);
                float h1 = fmaxf(fmaf(dc, a1, bfhi(ur.x)), 0.0f);
                float h2 = fmaxf(fmaf(dc, a2, bflo(ur.y)), 0.0f);
                float h3 = fmaxf(fmaf(dc, a3, bfhi(ur.y)), 0.0f);
                // bf16 round-trip: accumulate exactly the bits old pool read
                uint2 hb = make_uint2(pack_bf16(h0, h1), pack_bf16(h2, h3));
                p0 += bflo(hb.x);
                p1 += bfhi(hb.x);
                p2 += bflo(hb.y);
                p3 += bfhi(hb.y);
                if (d4 == 0) pc += 1.0f;
            }
        }
    }
    if (gcur >= 0 && lane < 16) {
        atomicAdd(&sAcc[gcur * 64 + d4 * 4 + 0], p0);
        atomicAdd(&sAcc[gcur * 64 + d4 * 4 + 1], p1);
        atomicAdd(&sAcc[gcur * 64 + d4 * 4 + 2], p2);
        atomicAdd(&sAcc[gcur * 64 + d4 * 4 + 3], p3);
        if (d4 == 0) atomicAdd(&sCnt[gcur], pc);
    }
    __syncthreads();
    for (int i = t; i < 4096; i += 256) {
        float v = sAcc[i];
        if (v != 0.0f) atomicAdd(&pooled[i], v);
    }
    if (t < 64) {
        float v = sCnt[t];
        if (v != 0.0f) atomicAdd(&cnt[t], v);
    }
}

// ---------------- out[g,o] = (pooled[g,:]/max(cnt,1)) @ fcw + fcb ----------------
__global__ void final_fc(const float* __restrict__ pooled, const float* __restrict__ cnt,
                         const float* __restrict__ fcw, const float* __restrict__ fcb,
                         float* __restrict__ out) {
    int idx = blockIdx.x * 256 + threadIdx.x;
    if (idx >= 64 * 32) return;
    int g = idx >> 5, o = idx & 31;
    float c = fmaxf(cnt[g], 1.0f);
    float acc = 0.0f;
#pragma unroll
    for (int k = 0; k < 64; ++k) acc = fmaf(pooled[g * 64 + k], fcw[k * 32 + o], acc);
    out[idx] = acc / c + fcb[o];
}

extern "C" void kernel_launch(void* const* d_in, const int* in_sizes, int n_in,
                              void* d_out, int out_size, void* d_ws, size_t ws_size,
                              hipStream_t stream) {
    const float* x       = (const float*)d_in[0];
    const int*   eidx    = (const int*)d_in[1];
    const int*   batch   = (const int*)d_in[2];
    const float* w1_init = (const float*)d_in[3];
    const float* w1_root = (const float*)d_in[4];
    const float* b1      = (const float*)d_in[5];
    const float* w2_init = (const float*)d_in[6];
    const float* w2_root = (const float*)d_in[7];
    const float* b2      = (const float*)d_in[8];
    const float* fc_w    = (const float*)d_in[9];
    const float* fc_b    = (const float*)d_in[10];
    float* out = (float*)d_out;

    const int N = in_sizes[0] / 64;
    const int E = in_sizes[1] / 2;
    const int* row = eidx;
    const int* col = eidx + E;

    const int B = (N + NB - 1) / NB;  // 391 buckets

    // workspace (4-byte units):
    // bpack(B*CAP) | es(B*CAP) | [zeroed: bcnt(MAXB) | pooled(4096) | cnt(64)]
    // | nstart(N) | ndeg(N) | dinv(N) | wt(16384) | Ts1(N*32) | Rs1(N*32)
    // | T2(N*32) | R2(N*32)
    uint32* bpack = (uint32*)d_ws;
    int*   es     = (int*)(bpack + (size_t)B * CAP);
    int*   bcnt   = es + (size_t)B * CAP;
    float* pooled = (float*)(bcnt + MAXB);
    float* cnt    = pooled + 64 * 64;
    int*   nstart = (int*)(cnt + 64);
    int*   ndeg   = nstart + N;
    float* dinv   = (float*)(ndeg + N);
    uint32* wtU   = (uint32*)(dinv + N);            // 16384 uints (64 KB)
    uint32* Ts1   = wtU + 16384;                    // N*32
    uint32* Rs1   = Ts1 + (size_t)N * 32;           // N*32
    uint32* T2    = Rs1 + (size_t)N * 32;           // N*32
    uint32* R2    = T2 + (size_t)N * 32;            // N*32
    ushort16* wt  = (ushort16*)wtU;

    hipMemsetAsync(bcnt, 0, (size_t)(MAXB + 64 * 64 + 64) * sizeof(int), stream);

    // bucket + fused weight prep
    const int EB = (E + P1_CHUNK - 1) / P1_CHUNK;
    bucket_kernel<<<128 + EB, 256, 0, stream>>>(row, col, bpack, bcnt, E,
                                                w1_init, w1_root, w2_init, w2_root, wt);

    // CSR build + fused layer-1 gemm
    csr_gemm<<<B, 1024, 0, stream>>>(bpack, bcnt, es, nstart, ndeg, dinv,
                                     x, wt, b1, (ushort16*)Ts1, (ushort16*)Rs1, N);

    // gather1 + fused layer-2 gemm
    gather_gemm<<<(N + 63) / 64, 256, 0, stream>>>(
        (const uint2*)Ts1, (const uint2*)Rs1, es, nstart, ndeg, dinv,
        wt + (size_t)4 * 4096, b2, (ushort16*)T2, (ushort16*)R2, N);

    // gather2 + mean-pool (H never materialized)
    gather_pool<<<(N + 63) / 64, 256, 0, stream>>>(
        (const uint2*)T2, (const uint2*)R2, es, nstart, ndeg, dinv,
        batch, pooled, cnt, N);

    // FC
    final_fc<<<(64 * 32 + 255) / 256, 256, 0, stream>>>(pooled, cnt, fc_w, fc_b, out);
}